// Round 1
// baseline (3056.214 us; speedup 1.0000x reference)
//
#include <hip/hip_runtime.h>
#include <math.h>

#define T 2048
#define NTOK 32768   // 2 dirs * 8 batch * 2048
#define CHUNK 128
#define NCH 16

// ---------------- prep: x (8,64,2048) -> h[dir,b,t,m], backward flipped ----------------
__global__ void k_prep(const float* __restrict__ x, float* __restrict__ h) {
  int idx = blockIdx.x*256 + threadIdx.x;       // NTOK*64
  int m   = idx & 63;
  int tok = idx >> 6;
  int t   = tok & (T-1);
  int b   = (tok >> 11) & 7;
  int dir = tok >> 14;
  int tt  = dir ? (T-1-t) : t;
  h[idx] = x[(b*64 + m)*2048 + tt];
}

// ---------------- K1: residual update + LN + in_proj (xz) ----------------
__global__ void k1(const float* __restrict__ h, float* __restrict__ res,
                   float* __restrict__ xr, float* __restrict__ zb,
                   const float* __restrict__ in_w, const float* __restrict__ nw,
                   const float* __restrict__ nb, int layer) {
  int wid = threadIdx.x >> 6, lane = threadIdx.x & 63;
  int tok = blockIdx.x*4 + wid;
  int dir = tok >> 14;
  __shared__ float vbuf[4][64];
  float hv = h[tok*64 + lane];
  float r  = (layer == 0) ? hv : hv + res[tok*64 + lane];
  res[tok*64 + lane] = r;
  float sum = r;
  #pragma unroll
  for (int o = 32; o > 0; o >>= 1) sum += __shfl_xor(sum, o);
  float mean = sum * (1.f/64.f);
  float dv = (r-mean)*(r-mean);
  #pragma unroll
  for (int o = 32; o > 0; o >>= 1) dv += __shfl_xor(dv, o);
  float inv = rsqrtf(dv*(1.f/64.f) + 1e-5f);
  int wb = (dir*4 + layer)*64;
  float v = (r-mean)*inv*nw[wb+lane] + nb[wb+lane];
  vbuf[wid][lane] = v;
  __syncthreads();
  const float* W = in_w + (dir*4 + layer)*256*64;
  float a0=0.f, a1=0.f, a2=0.f, a3=0.f;
  for (int d = 0; d < 64; ++d) {
    float vv = vbuf[wid][d];
    a0 += vv * W[(lane      )*64 + d];
    a1 += vv * W[(lane +  64)*64 + d];
    a2 += vv * W[(lane + 128)*64 + d];
    a3 += vv * W[(lane + 192)*64 + d];
  }
  xr[tok*128 + lane]      = a0;
  xr[tok*128 + 64 + lane] = a1;
  zb[tok*128 + lane]      = a2;
  zb[tok*128 + 64 + lane] = a3;
}

// ---------------- K2: causal depthwise conv + silu + x_proj + dt ----------------
__global__ void k2(const float* __restrict__ xr, float* __restrict__ xp,
                   float* __restrict__ dtb, float* __restrict__ bc,
                   const float* __restrict__ conv_w, const float* __restrict__ conv_b,
                   const float* __restrict__ xproj_w, const float* __restrict__ dt_w,
                   const float* __restrict__ dt_b, int layer) {
  int tok = blockIdx.x;
  int d = threadIdx.x;          // 128
  int t = tok & (T-1);
  int dir = tok >> 14;
  int pb = dir*4 + layer;
  __shared__ __align__(16) float xs[128];
  __shared__ float dbl[36];
  const float* cw = conv_w + (pb*128 + d)*4;
  float acc = conv_b[pb*128 + d];
  #pragma unroll
  for (int k = 0; k < 4; ++k) {
    int tt = t - 3 + k;
    if (tt >= 0) acc += xr[(tok-3+k)*128 + d] * cw[k];
  }
  float xv = acc / (1.f + expf(-acc));
  xs[d] = xv;
  xp[tok*128 + d] = xv;
  __syncthreads();
  if (d < 36) {
    const float4* P = (const float4*)(xproj_w + (pb*36 + d)*128);
    const float4* X = (const float4*)xs;
    float s = 0.f;
    #pragma unroll 8
    for (int k = 0; k < 32; ++k) {
      float4 pv = P[k]; float4 xv4 = X[k];
      s += pv.x*xv4.x + pv.y*xv4.y + pv.z*xv4.z + pv.w*xv4.w;
    }
    dbl[d] = s;
  }
  __syncthreads();
  const float* DW = dt_w + (pb*128 + d)*4;
  float dpre = dt_b[pb*128 + d] + dbl[0]*DW[0] + dbl[1]*DW[1] + dbl[2]*DW[2] + dbl[3]*DW[3];
  float sp = fmaxf(dpre, 0.f) + log1pf(expf(-fabsf(dpre)));
  dtb[tok*128 + d] = sp;
  if (d < 32) bc[tok*32 + d] = dbl[4 + d];
}

// ---------------- K3a: per-chunk local scan (init 0) -> hend, cumdecay P ----------------
__global__ void k3a(const float* __restrict__ xp, const float* __restrict__ dtb,
                    const float* __restrict__ bc, float* __restrict__ hend,
                    float* __restrict__ Pst, const float* __restrict__ A_log, int layer) {
  int blk = blockIdx.x;           // ((dir*8+b)*16 + c)
  int c  = blk & 15;
  int db = blk >> 4;
  int dir = db >> 3;
  int tid = threadIdx.x;          // 256
  int d = tid >> 1, s0 = (tid & 1)*8;
  int pb = dir*4 + layer;
  float A[8], hs[8], P[8];
  #pragma unroll
  for (int s = 0; s < 8; ++s) {
    A[s] = -expf(A_log[(pb*128 + d)*16 + s0 + s]);
    hs[s] = 0.f; P[s] = 1.f;
  }
  int tok0 = db*T + c*CHUNK;
  for (int t = 0; t < CHUNK; ++t) {
    int tok = tok0 + t;
    float dtv = dtb[tok*128 + d];
    float xv  = xp[tok*128 + d];
    float dtx = dtv*xv;
    #pragma unroll
    for (int s = 0; s < 8; ++s) {
      float Bv = bc[tok*32 + s0 + s];
      float dA = expf(dtv*A[s]);
      hs[s] = dA*hs[s] + dtx*Bv;
      P[s] *= dA;
    }
  }
  int base = blk*2048 + d*16 + s0;
  #pragma unroll
  for (int s = 0; s < 8; ++s) { hend[base+s] = hs[s]; Pst[base+s] = P[s]; }
}

// ---------------- K3b: prefix across chunks ----------------
__global__ void k3b(const float* __restrict__ hend, const float* __restrict__ Pst,
                    float* __restrict__ Sinit) {
  int db = blockIdx.x;           // 16
  int e0 = threadIdx.x * 8;      // 256 threads * 8 = 2048 entries
  float init[8];
  #pragma unroll
  for (int i = 0; i < 8; ++i) init[i] = 0.f;
  for (int c = 0; c < NCH; ++c) {
    int base = (db*16 + c)*2048 + e0;
    #pragma unroll
    for (int i = 0; i < 8; ++i) {
      Sinit[base+i] = init[i];
      init[i] = Pst[base+i]*init[i] + hend[base+i];
    }
  }
}

// ---------------- K3c: re-scan with true init, emit y ----------------
__global__ void k3c(const float* __restrict__ xp, const float* __restrict__ dtb,
                    const float* __restrict__ bc, const float* __restrict__ zb,
                    const float* __restrict__ Sinit, float* __restrict__ y,
                    const float* __restrict__ A_log, const float* __restrict__ Dp, int layer) {
  int blk = blockIdx.x;
  int c  = blk & 15;
  int db = blk >> 4;
  int dir = db >> 3;
  int tid = threadIdx.x;
  int d = tid >> 1, p = tid & 1, s0 = p*8;
  int pb = dir*4 + layer;
  float A[8], hs[8];
  int sbase = blk*2048 + d*16 + s0;
  #pragma unroll
  for (int s = 0; s < 8; ++s) {
    A[s] = -expf(A_log[(pb*128 + d)*16 + s0 + s]);
    hs[s] = Sinit[sbase + s];
  }
  float Dv = Dp[pb*128 + d];
  int tok0 = db*T + c*CHUNK;
  for (int t = 0; t < CHUNK; ++t) {
    int tok = tok0 + t;
    float dtv = dtb[tok*128 + d];
    float xv  = xp[tok*128 + d];
    float zv  = zb[tok*128 + d];
    float dtx = dtv*xv;
    float acc = 0.f;
    #pragma unroll
    for (int s = 0; s < 8; ++s) {
      float Bv = bc[tok*32 + s0 + s];
      float Cv = bc[tok*32 + 16 + s0 + s];
      float dA = expf(dtv*A[s]);
      hs[s] = dA*hs[s] + dtx*Bv;
      acc += hs[s]*Cv;
    }
    acc += __shfl_xor(acc, 1);
    if (p == 0) {
      y[tok*128 + d] = (acc + xv*Dv) * (zv/(1.f + expf(-zv)));
    }
  }
}

// ---------------- K4: out projection ----------------
__global__ void k4(const float* __restrict__ y, float* __restrict__ h,
                   const float* __restrict__ out_w, int layer) {
  int wid = threadIdx.x >> 6, lane = threadIdx.x & 63;
  int tok = blockIdx.x*4 + wid;
  int dir = tok >> 14;
  __shared__ __align__(16) float ys[4][128];
  ys[wid][lane]      = y[tok*128 + lane];
  ys[wid][64 + lane] = y[tok*128 + 64 + lane];
  __syncthreads();
  const float* W = out_w + (dir*4 + layer)*64*128 + lane*128;
  float a = 0.f;
  for (int k = 0; k < 128; ++k) a += ys[wid][k]*W[k];
  h[tok*64 + lane] = a;
}

// ---------------- K5: final residual add + LN + pool logits ----------------
__global__ void k5(const float* __restrict__ h, const float* __restrict__ res,
                   float* __restrict__ hfin, float* __restrict__ logits,
                   const float* __restrict__ nfw, const float* __restrict__ nfb,
                   const float* __restrict__ fpw, const float* __restrict__ fpb,
                   const float* __restrict__ bpw, const float* __restrict__ bpb) {
  int wid = threadIdx.x >> 6, lane = threadIdx.x & 63;
  int tok = blockIdx.x*4 + wid;
  int dir = tok >> 14;
  float r = h[tok*64 + lane] + res[tok*64 + lane];
  float sum = r;
  #pragma unroll
  for (int o = 32; o > 0; o >>= 1) sum += __shfl_xor(sum, o);
  float mean = sum * (1.f/64.f);
  float dv = (r-mean)*(r-mean);
  #pragma unroll
  for (int o = 32; o > 0; o >>= 1) dv += __shfl_xor(dv, o);
  float inv = rsqrtf(dv*(1.f/64.f) + 1e-5f);
  float v = (r-mean)*inv*nfw[lane] + nfb[lane];
  hfin[tok*64 + lane] = v;
  float lg = v * (dir ? bpw[lane] : fpw[lane]);
  #pragma unroll
  for (int o = 32; o > 0; o >>= 1) lg += __shfl_xor(lg, o);
  if (lane == 0) logits[tok] = lg + (dir ? bpb[0] : fpb[0]);
}

// ---------------- K6: softmax over t + weighted pool ----------------
__global__ void k6(const float* __restrict__ hfin, const float* __restrict__ logits,
                   float* __restrict__ pooled) {
  int blk = blockIdx.x;           // 16 = dir*8+b
  int tid = threadIdx.x;          // 256
  int tok0 = blk*T;
  __shared__ float red[256];
  float mx = -1e30f;
  for (int t = tid; t < T; t += 256) mx = fmaxf(mx, logits[tok0 + t]);
  red[tid] = mx; __syncthreads();
  for (int o = 128; o > 0; o >>= 1) { if (tid < o) red[tid] = fmaxf(red[tid], red[tid+o]); __syncthreads(); }
  mx = red[0]; __syncthreads();
  float sm = 0.f;
  for (int t = tid; t < T; t += 256) sm += expf(logits[tok0 + t] - mx);
  red[tid] = sm; __syncthreads();
  for (int o = 128; o > 0; o >>= 1) { if (tid < o) red[tid] += red[tid+o]; __syncthreads(); }
  float inv = 1.f/red[0];
  __syncthreads();
  int w = tid >> 6, m = tid & 63;
  float pacc = 0.f;
  for (int t = w; t < T; t += 4) {
    float a = expf(logits[tok0 + t] - mx)*inv;
    pacc += a * hfin[(tok0 + t)*64 + m];
  }
  red[tid] = pacc; __syncthreads();
  if (w == 0) pooled[blk*64 + m] = red[m] + red[64+m] + red[128+m] + red[192+m];
}

// ---------------- K7: head ----------------
__global__ void k7(const float* __restrict__ pooled, float* __restrict__ out,
                   const float* __restrict__ llw, const float* __restrict__ llb) {
  int idx = blockIdx.x*256 + threadIdx.x;
  if (idx >= 512) return;
  int b = idx >> 6, j = idx & 63;
  float a = llb[j];
  for (int d = 0; d < 64; ++d) {
    a += pooled[b*64 + d]       * llw[j*128 + d];
    a += pooled[(8+b)*64 + d]   * llw[j*128 + 64 + d];
  }
  out[idx] = a;
}

extern "C" void kernel_launch(void* const* d_in, const int* in_sizes, int n_in,
                              void* d_out, int out_size, void* d_ws, size_t ws_size,
                              hipStream_t stream) {
  const float* x      = (const float*)d_in[0];
  const float* in_w   = (const float*)d_in[1];
  const float* conv_w = (const float*)d_in[2];
  const float* conv_b = (const float*)d_in[3];
  const float* xproj_w= (const float*)d_in[4];
  const float* dt_w   = (const float*)d_in[5];
  const float* dt_b   = (const float*)d_in[6];
  const float* A_log  = (const float*)d_in[7];
  const float* Dp     = (const float*)d_in[8];
  const float* out_w  = (const float*)d_in[9];
  const float* nw     = (const float*)d_in[10];
  const float* nb     = (const float*)d_in[11];
  const float* nfw    = (const float*)d_in[12];
  const float* nfb    = (const float*)d_in[13];
  const float* fpw    = (const float*)d_in[14];
  const float* fpb    = (const float*)d_in[15];
  const float* bpw    = (const float*)d_in[16];
  const float* bpb    = (const float*)d_in[17];
  const float* llw    = (const float*)d_in[18];
  const float* llb    = (const float*)d_in[19];
  float* ws  = (float*)d_ws;
  float* h     = ws + 0;
  float* res   = ws + 2097152;
  float* xr    = ws + 4194304;    // x_raw, later y
  float* zb    = ws + 8388608;
  float* xp    = ws + 12582912;
  float* dtb   = ws + 16777216;   // later hfin
  float* bc    = ws + 20971520;
  float* logits= ws + 22020096;
  float* pooled= ws + 22052864;
  float* hend  = ws + 22053888;
  float* Pst   = ws + 22578176;
  float* sinit = ws + 23102464;
  float* out   = (float*)d_out;

  k_prep<<<dim3(8192), dim3(256), 0, stream>>>(x, h);
  for (int layer = 0; layer < 4; ++layer) {
    k1 <<<dim3(8192),  dim3(256), 0, stream>>>(h, res, xr, zb, in_w, nw, nb, layer);
    k2 <<<dim3(NTOK),  dim3(128), 0, stream>>>(xr, xp, dtb, bc, conv_w, conv_b, xproj_w, dt_w, dt_b, layer);
    k3a<<<dim3(256),   dim3(256), 0, stream>>>(xp, dtb, bc, hend, Pst, A_log, layer);
    k3b<<<dim3(16),    dim3(256), 0, stream>>>(hend, Pst, sinit);
    k3c<<<dim3(256),   dim3(256), 0, stream>>>(xp, dtb, bc, zb, sinit, xr, A_log, Dp, layer);
    k4 <<<dim3(8192),  dim3(256), 0, stream>>>(xr, h, out_w, layer);
  }
  k5<<<dim3(8192), dim3(256), 0, stream>>>(h, res, dtb, logits, nfw, nfb, fpw, fpb, bpw, bpb);
  k6<<<dim3(16),   dim3(256), 0, stream>>>(dtb, logits, pooled);
  k7<<<dim3(2),    dim3(256), 0, stream>>>(pooled, out, llw, llb);
}

// Round 2
// 932.034 us; speedup vs baseline: 3.2791x; 3.2791x over previous
//
#include <hip/hip_runtime.h>
#include <math.h>

#define T 2048
#define NTOK 32768   // 2 dirs * 8 batch * 2048
#define CHUNK 64
#define NCH 32
#define LOG2E 1.4426950408889634f

// ---------------- prep: x (8,64,2048) -> h[dir,b,t,m], backward flipped ----------------
__global__ void k_prep(const float* __restrict__ x, float* __restrict__ h) {
  int idx = blockIdx.x*256 + threadIdx.x;       // NTOK*64
  int m   = idx & 63;
  int tok = idx >> 6;
  int t   = tok & (T-1);
  int b   = (tok >> 11) & 7;
  int dir = tok >> 14;
  int tt  = dir ? (T-1-t) : t;
  h[idx] = x[(b*64 + m)*2048 + tt];
}

// ---------------- K1: residual + LN + in_proj; 64 tokens/block, W rows in regs ----------------
__global__ __launch_bounds__(256) void k1(const float* __restrict__ h, float* __restrict__ res,
                   float* __restrict__ xr, float* __restrict__ zb,
                   const float* __restrict__ in_w, const float* __restrict__ nw,
                   const float* __restrict__ nb, int layer) {
  int tok0 = blockIdx.x * 64;
  int dir = tok0 >> 14;
  int tid = threadIdx.x;
  int wid = tid >> 6, lane = tid & 63;
  __shared__ __align__(16) float vbuf[64][64];
  int wb = (dir*4 + layer)*64;
  float nwv = nw[wb+lane], nbv = nb[wb+lane];
  // phase A: LN for 16 tokens per wave
  for (int i = 0; i < 16; ++i) {
    int tl = wid*16 + i;
    int tok = tok0 + tl;
    float hv = h[tok*64 + lane];
    float r  = (layer == 0) ? hv : hv + res[tok*64 + lane];
    res[tok*64 + lane] = r;
    float sum = r;
    #pragma unroll
    for (int o = 32; o > 0; o >>= 1) sum += __shfl_xor(sum, o);
    float mean = sum * (1.f/64.f);
    float df = r - mean;
    float dv = df*df;
    #pragma unroll
    for (int o = 32; o > 0; o >>= 1) dv += __shfl_xor(dv, o);
    float inv = rsqrtf(dv*(1.f/64.f) + 1e-5f);
    vbuf[tl][lane] = df*inv*nwv + nbv;
  }
  __syncthreads();
  // phase B: thread = output row (256 rows of in_w)
  const float4* W4 = (const float4*)(in_w + (dir*4 + layer)*256*64 + tid*64);
  float4 w[16];
  #pragma unroll
  for (int i = 0; i < 16; ++i) w[i] = W4[i];
  for (int t = 0; t < 64; ++t) {
    const float4* v4 = (const float4*)(&vbuf[t][0]);
    float a = 0.f;
    #pragma unroll
    for (int i = 0; i < 16; ++i) {
      float4 vv = v4[i];
      a += vv.x*w[i].x + vv.y*w[i].y + vv.z*w[i].z + vv.w*w[i].w;
    }
    int tok = tok0 + t;
    if (tid < 128) xr[tok*128 + tid] = a;
    else           zb[tok*128 + tid - 128] = a;
  }
}

// ---------------- K2: conv + silu + x_proj + dt; 32 tokens/block ----------------
#define XSP 132
__global__ __launch_bounds__(256) void k2(const float* __restrict__ xr, float* __restrict__ xp,
                   float* __restrict__ dtb, float* __restrict__ bc,
                   const float* __restrict__ conv_w, const float* __restrict__ conv_b,
                   const float* __restrict__ xproj_w, const float* __restrict__ dt_w,
                   const float* __restrict__ dt_b, int layer) {
  int tok0 = blockIdx.x * 32;
  int t0 = tok0 & (T-1);
  int dir = tok0 >> 14;
  int pb = dir*4 + layer;
  int tid = threadIdx.x;
  __shared__ __align__(16) float xin[35][128];
  __shared__ __align__(16) float xs[32][XSP];
  __shared__ float dbl[32][36];
  // load input tile (tok0-3 .. tok0+31)
  for (int i = tid; i < 35*128; i += 256) {
    int r = i >> 7, c = i & 127;
    int tt = t0 - 3 + r;
    xin[r][c] = (tt >= 0) ? xr[(tok0-3+r)*128 + c] : 0.f;
  }
  __syncthreads();
  // conv + silu
  int d = tid & 127, half = tid >> 7;
  const float* cw = conv_w + (pb*128 + d)*4;
  float c0 = cw[0], c1 = cw[1], c2 = cw[2], c3 = cw[3];
  float cb = conv_b[pb*128 + d];
  for (int i = 0; i < 16; ++i) {
    int tl = i*2 + half;
    float acc = cb + xin[tl][d]*c0 + xin[tl+1][d]*c1 + xin[tl+2][d]*c2 + xin[tl+3][d]*c3;
    float xv = acc / (1.f + __expf(-acc));
    xs[tl][d] = xv;
    xp[(tok0+tl)*128 + d] = xv;
  }
  __syncthreads();
  // x_proj: 32 tokens x 36 outputs
  const float* XW = xproj_w + pb*36*128;
  for (int p = tid; p < 1152; p += 256) {
    int j = p >> 5, tl = p & 31;
    const float4* xv4 = (const float4*)(&xs[tl][0]);
    const float4* wv4 = (const float4*)(XW + j*128);
    float s = 0.f;
    #pragma unroll 8
    for (int k = 0; k < 32; ++k) {
      float4 a = xv4[k], b = wv4[k];
      s += a.x*b.x + a.y*b.y + a.z*b.z + a.w*b.w;
    }
    dbl[tl][j] = s;
  }
  __syncthreads();
  // dt path
  const float* DW = dt_w + (pb*128 + d)*4;
  float dw0 = DW[0], dw1 = DW[1], dw2 = DW[2], dw3 = DW[3];
  float dtbv = dt_b[pb*128 + d];
  for (int i = 0; i < 16; ++i) {
    int tl = i*2 + half;
    float dpre = dtbv + dbl[tl][0]*dw0 + dbl[tl][1]*dw1 + dbl[tl][2]*dw2 + dbl[tl][3]*dw3;
    float sp = fmaxf(dpre, 0.f) + log1pf(__expf(-fabsf(dpre)));
    dtb[(tok0+tl)*128 + d] = sp;
  }
  for (int p = tid; p < 1024; p += 256) {
    int tl = p >> 5, i = p & 31;
    bc[(tok0+tl)*32 + i] = dbl[tl][4 + i];
  }
}

// ---------------- K3a: per-chunk local scan -> hend, cumdecay P ----------------
__global__ __launch_bounds__(256) void k3a(const float* __restrict__ xp, const float* __restrict__ dtb,
                    const float* __restrict__ bc, float* __restrict__ hend,
                    float* __restrict__ Pst, const float* __restrict__ A_log, int layer) {
  int blk = blockIdx.x;           // db*NCH + c
  int c  = blk & (NCH-1);
  int db = blk >> 5;
  int dir = db >> 3;
  int tid = threadIdx.x;
  int d = tid >> 1, s0 = (tid & 1)*8;
  int pb = dir*4 + layer;
  float Ae[8], hs[8], P[8];
  #pragma unroll
  for (int s = 0; s < 8; ++s) {
    Ae[s] = -__expf(A_log[(pb*128 + d)*16 + s0 + s]) * LOG2E;
    hs[s] = 0.f; P[s] = 1.f;
  }
  int tok0 = db*T + c*CHUNK;
  for (int t = 0; t < CHUNK; ++t) {
    int tok = tok0 + t;
    float dtv = dtb[tok*128 + d];
    float xv  = xp[tok*128 + d];
    float dtx = dtv*xv;
    const float4* B4 = (const float4*)(bc + tok*32 + s0);
    float4 b0 = B4[0], b1 = B4[1];
    float bv[8] = {b0.x,b0.y,b0.z,b0.w,b1.x,b1.y,b1.z,b1.w};
    #pragma unroll
    for (int s = 0; s < 8; ++s) {
      float dA = exp2f(dtv*Ae[s]);
      P[s] *= dA;
      hs[s] = dA*hs[s] + dtx*bv[s];
    }
  }
  int base = blk*2048 + d*16 + s0;
  #pragma unroll
  for (int s = 0; s < 8; ++s) { hend[base+s] = hs[s]; Pst[base+s] = P[s]; }
}

// ---------------- K3b: prefix across chunks (Sinit written in-place over Pst) ----------------
__global__ __launch_bounds__(256) void k3b(const float* __restrict__ hend, float* __restrict__ Pst) {
  int db = blockIdx.x;           // 16
  int e0 = threadIdx.x * 8;
  float init[8];
  #pragma unroll
  for (int i = 0; i < 8; ++i) init[i] = 0.f;
  for (int c = 0; c < NCH; ++c) {
    int base = (db*NCH + c)*2048 + e0;
    #pragma unroll
    for (int i = 0; i < 8; ++i) {
      float p  = Pst[base+i];
      float he = hend[base+i];
      Pst[base+i] = init[i];
      init[i] = p*init[i] + he;
    }
  }
}

// ---------------- K3c: re-scan with true init, emit y ----------------
__global__ __launch_bounds__(256) void k3c(const float* __restrict__ xp, const float* __restrict__ dtb,
                    const float* __restrict__ bc, const float* __restrict__ zb,
                    const float* __restrict__ Sinit, float* __restrict__ y,
                    const float* __restrict__ A_log, const float* __restrict__ Dp, int layer) {
  int blk = blockIdx.x;
  int c  = blk & (NCH-1);
  int db = blk >> 5;
  int dir = db >> 3;
  int tid = threadIdx.x;
  int d = tid >> 1, p = tid & 1, s0 = p*8;
  int pb = dir*4 + layer;
  float Ae[8], hs[8];
  int sbase = blk*2048 + d*16 + s0;
  #pragma unroll
  for (int s = 0; s < 8; ++s) {
    Ae[s] = -__expf(A_log[(pb*128 + d)*16 + s0 + s]) * LOG2E;
    hs[s] = Sinit[sbase + s];
  }
  float Dv = Dp[pb*128 + d];
  int tok0 = db*T + c*CHUNK;
  for (int t = 0; t < CHUNK; ++t) {
    int tok = tok0 + t;
    float dtv = dtb[tok*128 + d];
    float xv  = xp[tok*128 + d];
    float zv  = zb[tok*128 + d];
    float dtx = dtv*xv;
    const float4* B4 = (const float4*)(bc + tok*32 + s0);
    const float4* C4 = (const float4*)(bc + tok*32 + 16 + s0);
    float4 b0 = B4[0], b1 = B4[1];
    float4 cc0 = C4[0], cc1 = C4[1];
    float bv[8] = {b0.x,b0.y,b0.z,b0.w,b1.x,b1.y,b1.z,b1.w};
    float cv[8] = {cc0.x,cc0.y,cc0.z,cc0.w,cc1.x,cc1.y,cc1.z,cc1.w};
    float acc = 0.f;
    #pragma unroll
    for (int s = 0; s < 8; ++s) {
      float dA = exp2f(dtv*Ae[s]);
      hs[s] = dA*hs[s] + dtx*bv[s];
      acc += hs[s]*cv[s];
    }
    acc += __shfl_xor(acc, 1);
    if (p == 0) {
      y[tok*128 + d] = (acc + xv*Dv) * (zv/(1.f + __expf(-zv)));
    }
  }
}

// ---------------- K4: out projection; 64 tokens/block, wave-per-16-tokens, W in regs ----------------
__global__ __launch_bounds__(256) void k4(const float* __restrict__ y, float* __restrict__ h,
                   const float* __restrict__ out_w, int layer) {
  int tok0 = blockIdx.x * 64;
  int dir = tok0 >> 14;
  int tid = threadIdx.x;
  int wid = tid >> 6, lane = tid & 63;
  __shared__ __align__(16) float ys[64][128];
  for (int i = tid; i < 64*32; i += 256) {
    int r = i >> 5, c4 = i & 31;
    ((float4*)(&ys[r][0]))[c4] = ((const float4*)(y + (tok0+r)*128))[c4];
  }
  const float4* W4 = (const float4*)(out_w + (dir*4 + layer)*64*128 + lane*128);
  float4 w[32];
  #pragma unroll
  for (int i = 0; i < 32; ++i) w[i] = W4[i];
  __syncthreads();
  for (int t = wid*16; t < wid*16 + 16; ++t) {
    const float4* yv4 = (const float4*)(&ys[t][0]);
    float a = 0.f;
    #pragma unroll
    for (int i = 0; i < 32; ++i) {
      float4 vv = yv4[i];
      a += vv.x*w[i].x + vv.y*w[i].y + vv.z*w[i].z + vv.w*w[i].w;
    }
    h[(tok0+t)*64 + lane] = a;
  }
}

// ---------------- K5: final residual add + LN + pool logits ----------------
__global__ void k5(const float* __restrict__ h, const float* __restrict__ res,
                   float* __restrict__ hfin, float* __restrict__ logits,
                   const float* __restrict__ nfw, const float* __restrict__ nfb,
                   const float* __restrict__ fpw, const float* __restrict__ fpb,
                   const float* __restrict__ bpw, const float* __restrict__ bpb) {
  int wid = threadIdx.x >> 6, lane = threadIdx.x & 63;
  int tok = blockIdx.x*4 + wid;
  int dir = tok >> 14;
  float r = h[tok*64 + lane] + res[tok*64 + lane];
  float sum = r;
  #pragma unroll
  for (int o = 32; o > 0; o >>= 1) sum += __shfl_xor(sum, o);
  float mean = sum * (1.f/64.f);
  float df = r - mean;
  float dv = df*df;
  #pragma unroll
  for (int o = 32; o > 0; o >>= 1) dv += __shfl_xor(dv, o);
  float inv = rsqrtf(dv*(1.f/64.f) + 1e-5f);
  float v = df*inv*nfw[lane] + nfb[lane];
  hfin[tok*64 + lane] = v;
  float lg = v * (dir ? bpw[lane] : fpw[lane]);
  #pragma unroll
  for (int o = 32; o > 0; o >>= 1) lg += __shfl_xor(lg, o);
  if (lane == 0) logits[tok] = lg + (dir ? bpb[0] : fpb[0]);
}

// ---------------- K6a: softmax stats per sequence ----------------
__global__ void k6a(const float* __restrict__ logits, float* __restrict__ stats) {
  int blk = blockIdx.x;           // 16
  int tid = threadIdx.x;          // 256
  int tok0 = blk*T;
  __shared__ float red[256];
  float mx = -1e30f;
  for (int t = tid; t < T; t += 256) mx = fmaxf(mx, logits[tok0 + t]);
  red[tid] = mx; __syncthreads();
  for (int o = 128; o > 0; o >>= 1) { if (tid < o) red[tid] = fmaxf(red[tid], red[tid+o]); __syncthreads(); }
  mx = red[0]; __syncthreads();
  float sm = 0.f;
  for (int t = tid; t < T; t += 256) sm += __expf(logits[tok0 + t] - mx);
  red[tid] = sm; __syncthreads();
  for (int o = 128; o > 0; o >>= 1) { if (tid < o) red[tid] += red[tid+o]; __syncthreads(); }
  if (tid == 0) { stats[blk] = mx; stats[16+blk] = 1.f/red[0]; }
}

// ---------------- K6b: sliced weighted pool ----------------
__global__ void k6b(const float* __restrict__ hfin, const float* __restrict__ logits,
                    const float* __restrict__ stats, float* __restrict__ pf) {
  int blk = blockIdx.x;            // 128 = seq*8 + slice
  int seq = blk >> 3, slice = blk & 7;
  int tid = threadIdx.x;
  int w = tid >> 6, m = tid & 63;
  float mx = stats[seq], inv = stats[16+seq];
  int tok0 = seq*T + slice*256;
  float pacc = 0.f;
  for (int t = w; t < 256; t += 4) {
    float a = __expf(logits[tok0 + t] - mx)*inv;
    pacc += a * hfin[(tok0 + t)*64 + m];
  }
  __shared__ float red[256];
  red[tid] = pacc; __syncthreads();
  if (w == 0) pf[(seq*64 + m)*8 + slice] = red[m] + red[64+m] + red[128+m] + red[192+m];
}

// ---------------- K6c: reduce slices ----------------
__global__ void k6c(const float* __restrict__ pf, float* __restrict__ pooled) {
  int i = blockIdx.x*256 + threadIdx.x;   // 1024
  if (i >= 1024) return;
  const float4* p4 = (const float4*)(pf + i*8);
  float4 a = p4[0], b = p4[1];
  pooled[i] = a.x+a.y+a.z+a.w+b.x+b.y+b.z+b.w;
}

// ---------------- K7: head ----------------
__global__ void k7(const float* __restrict__ pooled, float* __restrict__ out,
                   const float* __restrict__ llw, const float* __restrict__ llb) {
  int idx = blockIdx.x*256 + threadIdx.x;
  if (idx >= 512) return;
  int b = idx >> 6, j = idx & 63;
  float a = llb[j];
  for (int d = 0; d < 64; ++d) {
    a += pooled[b*64 + d]       * llw[j*128 + d];
    a += pooled[(8+b)*64 + d]   * llw[j*128 + 64 + d];
  }
  out[idx] = a;
}

extern "C" void kernel_launch(void* const* d_in, const int* in_sizes, int n_in,
                              void* d_out, int out_size, void* d_ws, size_t ws_size,
                              hipStream_t stream) {
  const float* x      = (const float*)d_in[0];
  const float* in_w   = (const float*)d_in[1];
  const float* conv_w = (const float*)d_in[2];
  const float* conv_b = (const float*)d_in[3];
  const float* xproj_w= (const float*)d_in[4];
  const float* dt_w   = (const float*)d_in[5];
  const float* dt_b   = (const float*)d_in[6];
  const float* A_log  = (const float*)d_in[7];
  const float* Dp     = (const float*)d_in[8];
  const float* out_w  = (const float*)d_in[9];
  const float* nw     = (const float*)d_in[10];
  const float* nb     = (const float*)d_in[11];
  const float* nfw    = (const float*)d_in[12];
  const float* nfb    = (const float*)d_in[13];
  const float* fpw    = (const float*)d_in[14];
  const float* fpb    = (const float*)d_in[15];
  const float* bpw    = (const float*)d_in[16];
  const float* bpb    = (const float*)d_in[17];
  const float* llw    = (const float*)d_in[18];
  const float* llb    = (const float*)d_in[19];
  float* ws  = (float*)d_ws;
  float* h     = ws + 0;          // 2M floats; hend/Pst aliased here during scan
  float* res   = ws + 2097152;    // 2M
  float* xr    = ws + 4194304;    // 4M: raw x, later y
  float* zb    = ws + 8388608;    // 4M
  float* xp    = ws + 12582912;   // 4M
  float* dtb   = ws + 16777216;   // 4M, later hfin
  float* bc    = ws + 20971520;   // 1M
  float* logits= ws + 22020096;   // 32768
  float* pf    = ws + 22052864;   // 8192
  float* pooled= ws + 22061056;   // 1024
  float* stats = ws + 22062080;   // 32
  float* hend  = h;               // 512*2048 = 1M (h is dead between k1 and k4)
  float* Pst   = h + 1048576;     // 1M (Sinit in-place)
  float* out   = (float*)d_out;

  k_prep<<<dim3(8192), dim3(256), 0, stream>>>(x, h);
  for (int layer = 0; layer < 4; ++layer) {
    k1 <<<dim3(512),   dim3(256), 0, stream>>>(h, res, xr, zb, in_w, nw, nb, layer);
    k2 <<<dim3(1024),  dim3(256), 0, stream>>>(xr, xp, dtb, bc, conv_w, conv_b, xproj_w, dt_w, dt_b, layer);
    k3a<<<dim3(512),   dim3(256), 0, stream>>>(xp, dtb, bc, hend, Pst, A_log, layer);
    k3b<<<dim3(16),    dim3(256), 0, stream>>>(hend, Pst);
    k3c<<<dim3(512),   dim3(256), 0, stream>>>(xp, dtb, bc, zb, Pst, xr, A_log, Dp, layer);
    k4 <<<dim3(512),   dim3(256), 0, stream>>>(xr, h, out_w, layer);
  }
  k5 <<<dim3(8192), dim3(256), 0, stream>>>(h, res, dtb, logits, nfw, nfb, fpw, fpb, bpw, bpb);
  k6a<<<dim3(16),   dim3(256), 0, stream>>>(logits, stats);
  k6b<<<dim3(128),  dim3(256), 0, stream>>>(dtb, logits, stats, pf);
  k6c<<<dim3(4),    dim3(256), 0, stream>>>(pf, pooled);
  k7 <<<dim3(2),    dim3(256), 0, stream>>>(pooled, out, llw, llb);
}

// Round 3
// 872.270 us; speedup vs baseline: 3.5037x; 1.0685x over previous
//
#include <hip/hip_runtime.h>
#include <math.h>

#define T 2048
#define NTOK 32768   // 2 dirs * 8 batch * 2048
#define CHUNK 64
#define NCH 32
#define LOG2E 1.4426950408889634f

// ---------------- prep: x (8,64,2048) -> h[dir,b,t,m], backward flipped ----------------
__global__ void k_prep(const float* __restrict__ x, float* __restrict__ h) {
  int idx = blockIdx.x*256 + threadIdx.x;       // NTOK*64
  int m   = idx & 63;
  int tok = idx >> 6;
  int t   = tok & (T-1);
  int b   = (tok >> 11) & 7;
  int dir = tok >> 14;
  int tt  = dir ? (T-1-t) : t;
  h[idx] = x[(b*64 + m)*2048 + tt];
}

// ---------------- kAe: Ae[pb][d][s] = -exp(A_log)*log2e ----------------
__global__ void kAe(const float* __restrict__ A_log, float* __restrict__ Ae) {
  int i = blockIdx.x*256 + threadIdx.x;   // 16384
  Ae[i] = -__expf(A_log[i]) * LOG2E;
}

// ---------------- K1: residual + LN + in_proj; 64 tokens/block, W rows in regs ----------------
__global__ __launch_bounds__(256) void k1(const float* __restrict__ h, float* __restrict__ res,
                   float* __restrict__ xr, float* __restrict__ zb,
                   const float* __restrict__ in_w, const float* __restrict__ nw,
                   const float* __restrict__ nb, int layer) {
  int tok0 = blockIdx.x * 64;
  int dir = tok0 >> 14;
  int tid = threadIdx.x;
  int wid = tid >> 6, lane = tid & 63;
  __shared__ __align__(16) float vbuf[64][64];
  int wb = (dir*4 + layer)*64;
  float nwv = nw[wb+lane], nbv = nb[wb+lane];
  for (int i = 0; i < 16; ++i) {
    int tl = wid*16 + i;
    int tok = tok0 + tl;
    float hv = h[tok*64 + lane];
    float r  = (layer == 0) ? hv : hv + res[tok*64 + lane];
    res[tok*64 + lane] = r;
    float sum = r;
    #pragma unroll
    for (int o = 32; o > 0; o >>= 1) sum += __shfl_xor(sum, o);
    float mean = sum * (1.f/64.f);
    float df = r - mean;
    float dv = df*df;
    #pragma unroll
    for (int o = 32; o > 0; o >>= 1) dv += __shfl_xor(dv, o);
    float inv = rsqrtf(dv*(1.f/64.f) + 1e-5f);
    vbuf[tl][lane] = df*inv*nwv + nbv;
  }
  __syncthreads();
  const float4* W4 = (const float4*)(in_w + (dir*4 + layer)*256*64 + tid*64);
  float4 w[16];
  #pragma unroll
  for (int i = 0; i < 16; ++i) w[i] = W4[i];
  for (int t = 0; t < 64; ++t) {
    const float4* v4 = (const float4*)(&vbuf[t][0]);
    float a = 0.f;
    #pragma unroll
    for (int i = 0; i < 16; ++i) {
      float4 vv = v4[i];
      a += vv.x*w[i].x + vv.y*w[i].y + vv.z*w[i].z + vv.w*w[i].w;
    }
    int tok = tok0 + t;
    if (tid < 128) xr[tok*128 + tid] = a;
    else           zb[tok*128 + tid - 128] = a;
  }
}

// ---------------- K2: conv + silu + x_proj + dt; 32 tokens/block ----------------
#define XSP 132
__global__ __launch_bounds__(256) void k2(const float* __restrict__ xr, float* __restrict__ xp,
                   float* __restrict__ dtb, float* __restrict__ bc,
                   const float* __restrict__ conv_w, const float* __restrict__ conv_b,
                   const float* __restrict__ xproj_w, const float* __restrict__ dt_w,
                   const float* __restrict__ dt_b, int layer) {
  int tok0 = blockIdx.x * 32;
  int t0 = tok0 & (T-1);
  int dir = tok0 >> 14;
  int pb = dir*4 + layer;
  int tid = threadIdx.x;
  __shared__ __align__(16) float xin[35][128];
  __shared__ __align__(16) float xs[32][XSP];
  __shared__ float dbl[32][36];
  for (int i = tid; i < 35*128; i += 256) {
    int r = i >> 7, c = i & 127;
    int tt = t0 - 3 + r;
    xin[r][c] = (tt >= 0) ? xr[(tok0-3+r)*128 + c] : 0.f;
  }
  __syncthreads();
  int d = tid & 127, half = tid >> 7;
  const float* cw = conv_w + (pb*128 + d)*4;
  float c0 = cw[0], c1 = cw[1], c2 = cw[2], c3 = cw[3];
  float cb = conv_b[pb*128 + d];
  for (int i = 0; i < 16; ++i) {
    int tl = i*2 + half;
    float acc = cb + xin[tl][d]*c0 + xin[tl+1][d]*c1 + xin[tl+2][d]*c2 + xin[tl+3][d]*c3;
    float xv = acc / (1.f + __expf(-acc));
    xs[tl][d] = xv;
    xp[(tok0+tl)*128 + d] = xv;
  }
  __syncthreads();
  const float* XW = xproj_w + pb*36*128;
  for (int p = tid; p < 1152; p += 256) {
    int j = p >> 5, tl = p & 31;
    const float4* xv4 = (const float4*)(&xs[tl][0]);
    const float4* wv4 = (const float4*)(XW + j*128);
    float s = 0.f;
    #pragma unroll 8
    for (int k = 0; k < 32; ++k) {
      float4 a = xv4[k], b = wv4[k];
      s += a.x*b.x + a.y*b.y + a.z*b.z + a.w*b.w;
    }
    dbl[tl][j] = s;
  }
  __syncthreads();
  const float* DW = dt_w + (pb*128 + d)*4;
  float dw0 = DW[0], dw1 = DW[1], dw2 = DW[2], dw3 = DW[3];
  float dtbv = dt_b[pb*128 + d];
  for (int i = 0; i < 16; ++i) {
    int tl = i*2 + half;
    float dpre = dtbv + dbl[tl][0]*dw0 + dbl[tl][1]*dw1 + dbl[tl][2]*dw2 + dbl[tl][3]*dw3;
    float sp = fmaxf(dpre, 0.f) + log1pf(__expf(-fabsf(dpre)));
    dtb[(tok0+tl)*128 + d] = sp;
  }
  for (int p = tid; p < 1024; p += 256) {
    int tl = p >> 5, i = p & 31;
    bc[(tok0+tl)*32 + i] = dbl[tl][4 + i];
  }
}

// ---------------- K3a: single fused chunk scan (LDS-staged) ----------------
// writes: y_local(+x*D) -> ylocal, cumdt -> dtb (in place), hend, Pst = exp2(Ae*cum_end)
__global__ __launch_bounds__(256) void k3a(const float* __restrict__ xp, float* __restrict__ dtb,
                    const float* __restrict__ bc, const float* __restrict__ Ae,
                    const float* __restrict__ Dp, float* __restrict__ ylocal,
                    float* __restrict__ hend, float* __restrict__ Pst, int layer) {
  int blk = blockIdx.x;           // db*NCH + c
  int c  = blk & (NCH-1);
  int db = blk >> 5;
  int dir = db >> 3;
  int pb = dir*4 + layer;
  int tid = threadIdx.x;
  int d = tid >> 1, p = tid & 1, s0 = p*8;
  __shared__ __align__(16) float sdt[CHUNK*128];
  __shared__ __align__(16) float sxp[CHUNK*128];
  __shared__ __align__(16) float sbc[CHUNK*32];
  int tok0 = db*T + c*CHUNK;
  {
    const float4* g1 = (const float4*)(dtb + (size_t)tok0*128);
    const float4* g2 = (const float4*)(xp  + (size_t)tok0*128);
    const float4* g3 = (const float4*)(bc  + (size_t)tok0*32);
    float4* s1 = (float4*)sdt; float4* s2 = (float4*)sxp; float4* s3 = (float4*)sbc;
    #pragma unroll
    for (int i = 0; i < 8; ++i) s1[tid + i*256] = g1[tid + i*256];
    #pragma unroll
    for (int i = 0; i < 8; ++i) s2[tid + i*256] = g2[tid + i*256];
    #pragma unroll
    for (int i = 0; i < 2; ++i) s3[tid + i*256] = g3[tid + i*256];
  }
  float ae[8];
  {
    const float4* A4 = (const float4*)(Ae + pb*2048 + d*16 + s0);
    float4 a0 = A4[0], a1 = A4[1];
    ae[0]=a0.x; ae[1]=a0.y; ae[2]=a0.z; ae[3]=a0.w;
    ae[4]=a1.x; ae[5]=a1.y; ae[6]=a1.z; ae[7]=a1.w;
  }
  float Dv = Dp[pb*128 + d];
  __syncthreads();
  float hs[8] = {0,0,0,0,0,0,0,0};
  float cum = 0.f;
  for (int t = 0; t < CHUNK; ++t) {
    float dtv = sdt[t*128 + d];
    float xv  = sxp[t*128 + d];
    cum += dtv;
    float dtx = dtv*xv;
    const float4* B4 = (const float4*)(sbc + t*32 + s0);
    const float4* C4 = (const float4*)(sbc + t*32 + 16 + s0);
    float4 b0=B4[0], b1=B4[1], cc0=C4[0], cc1=C4[1];
    float bv[8] = {b0.x,b0.y,b0.z,b0.w,b1.x,b1.y,b1.z,b1.w};
    float cv[8] = {cc0.x,cc0.y,cc0.z,cc0.w,cc1.x,cc1.y,cc1.z,cc1.w};
    float acc = 0.f;
    #pragma unroll
    for (int s = 0; s < 8; ++s) {
      float dA = exp2f(dtv*ae[s]);
      hs[s] = dA*hs[s] + dtx*bv[s];
      acc += hs[s]*cv[s];
    }
    acc += __shfl_xor(acc, 1);
    if (p == 0) {
      int tok = tok0 + t;
      ylocal[tok*128 + d] = acc + xv*Dv;
      dtb[tok*128 + d] = cum;
    }
  }
  int base = blk*2048 + d*16 + s0;
  #pragma unroll
  for (int s = 0; s < 8; ++s) { hend[base+s] = hs[s]; Pst[base+s] = exp2f(ae[s]*cum); }
}

// ---------------- K3b: prefix across chunks (Sinit in place over Pst); entry-parallel ----------------
__global__ __launch_bounds__(256) void k3b(const float* __restrict__ hend, float* __restrict__ Pst) {
  int db = blockIdx.x >> 3;       // 128 blocks: db*8 + slice
  int e  = (blockIdx.x & 7)*256 + threadIdx.x;
  float init = 0.f;
  #pragma unroll 4
  for (int c = 0; c < NCH; ++c) {
    int base = (db*NCH + c)*2048 + e;
    float pz = Pst[base];
    float he = hend[base];
    Pst[base] = init;
    init = pz*init + he;
  }
}

// ---------------- K3c: parallel correction + gate (no recurrence) ----------------
__global__ __launch_bounds__(256) void k3c(float* __restrict__ y, const float* __restrict__ cumdt,
                    const float* __restrict__ zb, const float* __restrict__ bc,
                    const float* __restrict__ Sinit, const float* __restrict__ Ae, int layer) {
  int tid = threadIdx.x;
  int tok = blockIdx.x*2 + (tid >> 7);
  int d = tid & 127;
  int dir = tok >> 14;
  int pb = dir*4 + layer;
  int sb = (tok >> 11)*NCH + ((tok & (T-1)) >> 6);
  float cum = cumdt[tok*128 + d];
  const float4* A4 = (const float4*)(Ae + pb*2048 + d*16);
  const float4* S4 = (const float4*)(Sinit + sb*2048 + d*16);
  const float4* C4 = (const float4*)(bc + tok*32 + 16);
  float acc = 0.f;
  #pragma unroll
  for (int q = 0; q < 4; ++q) {
    float4 a = A4[q], si = S4[q], cc = C4[q];
    acc += exp2f(a.x*cum)*si.x*cc.x;
    acc += exp2f(a.y*cum)*si.y*cc.y;
    acc += exp2f(a.z*cum)*si.z*cc.z;
    acc += exp2f(a.w*cum)*si.w*cc.w;
  }
  float yl = y[tok*128 + d];
  float zv = zb[tok*128 + d];
  y[tok*128 + d] = (yl + acc) * (zv/(1.f + __expf(-zv)));
}

// ---------------- K4: out projection ----------------
__global__ __launch_bounds__(256) void k4(const float* __restrict__ y, float* __restrict__ h,
                   const float* __restrict__ out_w, int layer) {
  int tok0 = blockIdx.x * 64;
  int dir = tok0 >> 14;
  int tid = threadIdx.x;
  int wid = tid >> 6, lane = tid & 63;
  __shared__ __align__(16) float ys[64][128];
  for (int i = tid; i < 64*32; i += 256) {
    int r = i >> 5, c4 = i & 31;
    ((float4*)(&ys[r][0]))[c4] = ((const float4*)(y + (tok0+r)*128))[c4];
  }
  const float4* W4 = (const float4*)(out_w + (dir*4 + layer)*64*128 + lane*128);
  float4 w[32];
  #pragma unroll
  for (int i = 0; i < 32; ++i) w[i] = W4[i];
  __syncthreads();
  for (int t = wid*16; t < wid*16 + 16; ++t) {
    const float4* yv4 = (const float4*)(&ys[t][0]);
    float a = 0.f;
    #pragma unroll
    for (int i = 0; i < 32; ++i) {
      float4 vv = yv4[i];
      a += vv.x*w[i].x + vv.y*w[i].y + vv.z*w[i].z + vv.w*w[i].w;
    }
    h[(tok0+t)*64 + lane] = a;
  }
}

// ---------------- K5: final residual add + LN + pool logits ----------------
__global__ void k5(const float* __restrict__ h, const float* __restrict__ res,
                   float* __restrict__ hfin, float* __restrict__ logits,
                   const float* __restrict__ nfw, const float* __restrict__ nfb,
                   const float* __restrict__ fpw, const float* __restrict__ fpb,
                   const float* __restrict__ bpw, const float* __restrict__ bpb) {
  int wid = threadIdx.x >> 6, lane = threadIdx.x & 63;
  int tok = blockIdx.x*4 + wid;
  int dir = tok >> 14;
  float r = h[tok*64 + lane] + res[tok*64 + lane];
  float sum = r;
  #pragma unroll
  for (int o = 32; o > 0; o >>= 1) sum += __shfl_xor(sum, o);
  float mean = sum * (1.f/64.f);
  float df = r - mean;
  float dv = df*df;
  #pragma unroll
  for (int o = 32; o > 0; o >>= 1) dv += __shfl_xor(dv, o);
  float inv = rsqrtf(dv*(1.f/64.f) + 1e-5f);
  float v = df*inv*nfw[lane] + nfb[lane];
  hfin[tok*64 + lane] = v;
  float lg = v * (dir ? bpw[lane] : fpw[lane]);
  #pragma unroll
  for (int o = 32; o > 0; o >>= 1) lg += __shfl_xor(lg, o);
  if (lane == 0) logits[tok] = lg + (dir ? bpb[0] : fpb[0]);
}

// ---------------- K6a: softmax stats per sequence ----------------
__global__ void k6a(const float* __restrict__ logits, float* __restrict__ stats) {
  int blk = blockIdx.x;           // 16
  int tid = threadIdx.x;          // 256
  int tok0 = blk*T;
  __shared__ float red[256];
  float mx = -1e30f;
  for (int t = tid; t < T; t += 256) mx = fmaxf(mx, logits[tok0 + t]);
  red[tid] = mx; __syncthreads();
  for (int o = 128; o > 0; o >>= 1) { if (tid < o) red[tid] = fmaxf(red[tid], red[tid+o]); __syncthreads(); }
  mx = red[0]; __syncthreads();
  float sm = 0.f;
  for (int t = tid; t < T; t += 256) sm += __expf(logits[tok0 + t] - mx);
  red[tid] = sm; __syncthreads();
  for (int o = 128; o > 0; o >>= 1) { if (tid < o) red[tid] += red[tid+o]; __syncthreads(); }
  if (tid == 0) { stats[blk] = mx; stats[16+blk] = 1.f/red[0]; }
}

// ---------------- K6b: sliced weighted pool ----------------
__global__ void k6b(const float* __restrict__ hfin, const float* __restrict__ logits,
                    const float* __restrict__ stats, float* __restrict__ pf) {
  int blk = blockIdx.x;            // 128 = seq*8 + slice
  int seq = blk >> 3, slice = blk & 7;
  int tid = threadIdx.x;
  int w = tid >> 6, m = tid & 63;
  float mx = stats[seq], inv = stats[16+seq];
  int tok0 = seq*T + slice*256;
  float pacc = 0.f;
  for (int t = w; t < 256; t += 4) {
    float a = __expf(logits[tok0 + t] - mx)*inv;
    pacc += a * hfin[(tok0 + t)*64 + m];
  }
  __shared__ float red[256];
  red[tid] = pacc; __syncthreads();
  if (w == 0) pf[(seq*64 + m)*8 + slice] = red[m] + red[64+m] + red[128+m] + red[192+m];
}

// ---------------- K6c: reduce slices ----------------
__global__ void k6c(const float* __restrict__ pf, float* __restrict__ pooled) {
  int i = blockIdx.x*256 + threadIdx.x;   // 1024
  if (i >= 1024) return;
  const float4* p4 = (const float4*)(pf + i*8);
  float4 a = p4[0], b = p4[1];
  pooled[i] = a.x+a.y+a.z+a.w+b.x+b.y+b.z+b.w;
}

// ---------------- K7: head ----------------
__global__ void k7(const float* __restrict__ pooled, float* __restrict__ out,
                   const float* __restrict__ llw, const float* __restrict__ llb) {
  int idx = blockIdx.x*256 + threadIdx.x;
  if (idx >= 512) return;
  int b = idx >> 6, j = idx & 63;
  float a = llb[j];
  for (int d = 0; d < 64; ++d) {
    a += pooled[b*64 + d]       * llw[j*128 + d];
    a += pooled[(8+b)*64 + d]   * llw[j*128 + 64 + d];
  }
  out[idx] = a;
}

extern "C" void kernel_launch(void* const* d_in, const int* in_sizes, int n_in,
                              void* d_out, int out_size, void* d_ws, size_t ws_size,
                              hipStream_t stream) {
  const float* x      = (const float*)d_in[0];
  const float* in_w   = (const float*)d_in[1];
  const float* conv_w = (const float*)d_in[2];
  const float* conv_b = (const float*)d_in[3];
  const float* xproj_w= (const float*)d_in[4];
  const float* dt_w   = (const float*)d_in[5];
  const float* dt_b   = (const float*)d_in[6];
  const float* A_log  = (const float*)d_in[7];
  const float* Dp     = (const float*)d_in[8];
  const float* out_w  = (const float*)d_in[9];
  const float* nw     = (const float*)d_in[10];
  const float* nb     = (const float*)d_in[11];
  const float* nfw    = (const float*)d_in[12];
  const float* nfb    = (const float*)d_in[13];
  const float* fpw    = (const float*)d_in[14];
  const float* fpb    = (const float*)d_in[15];
  const float* bpw    = (const float*)d_in[16];
  const float* bpb    = (const float*)d_in[17];
  const float* llw    = (const float*)d_in[18];
  const float* llb    = (const float*)d_in[19];
  float* ws  = (float*)d_ws;
  float* h     = ws + 0;          // 2M floats; hend/Pst aliased here during scan
  float* res   = ws + 2097152;    // 2M
  float* xr    = ws + 4194304;    // 4M: raw x -> y_local -> y
  float* zb    = ws + 8388608;    // 4M
  float* xp    = ws + 12582912;   // 4M
  float* dtb   = ws + 16777216;   // 4M: dt -> cumdt -> hfin
  float* bc    = ws + 20971520;   // 1M
  float* logits= ws + 22020096;   // 32768
  float* pf    = ws + 22052864;   // 8192
  float* pooled= ws + 22061056;   // 1024
  float* stats = ws + 22062080;   // 32
  float* AeBuf = ws + 22062112;   // 16384
  float* hend  = h;               // 512*2048 = 1M (h dead between k1 and k4)
  float* Pst   = h + 1048576;     // 1M (Sinit in place)
  float* out   = (float*)d_out;

  k_prep<<<dim3(8192), dim3(256), 0, stream>>>(x, h);
  kAe   <<<dim3(64),   dim3(256), 0, stream>>>(A_log, AeBuf);
  for (int layer = 0; layer < 4; ++layer) {
    k1 <<<dim3(512),   dim3(256), 0, stream>>>(h, res, xr, zb, in_w, nw, nb, layer);
    k2 <<<dim3(1024),  dim3(256), 0, stream>>>(xr, xp, dtb, bc, conv_w, conv_b, xproj_w, dt_w, dt_b, layer);
    k3a<<<dim3(512),   dim3(256), 0, stream>>>(xp, dtb, bc, AeBuf, Dp, xr, hend, Pst, layer);
    k3b<<<dim3(128),   dim3(256), 0, stream>>>(hend, Pst);
    k3c<<<dim3(16384), dim3(256), 0, stream>>>(xr, dtb, zb, bc, Pst, AeBuf, layer);
    k4 <<<dim3(512),   dim3(256), 0, stream>>>(xr, h, out_w, layer);
  }
  k5 <<<dim3(8192), dim3(256), 0, stream>>>(h, res, dtb, logits, nfw, nfb, fpw, fpb, bpw, bpb);
  k6a<<<dim3(16),   dim3(256), 0, stream>>>(logits, stats);
  k6b<<<dim3(128),  dim3(256), 0, stream>>>(dtb, logits, stats, pf);
  k6c<<<dim3(4),    dim3(256), 0, stream>>>(pf, pooled);
  k7 <<<dim3(2),    dim3(256), 0, stream>>>(pooled, out, llw, llb);
}

// Round 4
// 693.299 us; speedup vs baseline: 4.4082x; 1.2581x over previous
//
#include <hip/hip_runtime.h>
#include <math.h>

#define T 2048
#define NTOK 32768   // 2 dirs * 8 batch * 2048
#define CHUNK 64
#define NCH 32
#define LOG2E 1.4426950408889634f
#define DBLS 41      // padded stride for dbl[64][41]

// ---------------- prep: x (8,64,2048) -> h[dir,b,t,m], backward flipped ----------------
__global__ void k_prep(const float* __restrict__ x, float* __restrict__ h) {
  int idx = blockIdx.x*256 + threadIdx.x;       // NTOK*64
  int m   = idx & 63;
  int tok = idx >> 6;
  int t   = tok & (T-1);
  int b   = (tok >> 11) & 7;
  int dir = tok >> 14;
  int tt  = dir ? (T-1-t) : t;
  h[idx] = x[(b*64 + m)*2048 + tt];
}

// ---------------- kAe: Ae[pb][d][s] = -exp(A_log)*log2e ----------------
__global__ void kAe(const float* __restrict__ A_log, float* __restrict__ Ae) {
  int i = blockIdx.x*256 + threadIdx.x;   // 16384
  Ae[i] = -__expf(A_log[i]) * LOG2E;
}

// ============ kA: LN + in_proj + conv + x_proj + dt + local chunk scan ============
// block = 64 tokens = one chunk. LDS-resident pipeline.
// outputs: res_out, zb, ylocal(+x*D), cumdt, Cg[tok][16], hend, Pst
__global__ __launch_bounds__(256) void kA(
    const float* __restrict__ h, const float* __restrict__ res_in, float* __restrict__ res_out,
    float* __restrict__ zb, float* __restrict__ ylocal, float* __restrict__ cumdt,
    float* __restrict__ Cg, float* __restrict__ hend, float* __restrict__ Pst,
    const float* __restrict__ in_w, const float* __restrict__ nw, const float* __restrict__ nb,
    const float* __restrict__ conv_w, const float* __restrict__ conv_b,
    const float* __restrict__ xproj_w, const float* __restrict__ dt_w, const float* __restrict__ dt_b,
    const float* __restrict__ Ae, const float* __restrict__ Dp, int layer)
{
  __shared__ __align__(16) float A_[9216];  // xr[67][128] -> dblp[4][36][64] -> sdt[64][132]
  __shared__ __align__(16) float B_[8448];  // vbuf[67][64] -> xs[64][132]
  __shared__ __align__(16) float D_[64*DBLS]; // dbl
  int tid = threadIdx.x;
  int tok0 = blockIdx.x * 64;
  int t0 = tok0 & (T-1);
  int dir = tok0 >> 14;
  int pb = dir*4 + layer;
  int wid = tid >> 6, lane = tid & 63;

  // ---- P0: residual + LN for rows 0..66 (row r <-> token tok0-3+r) ----
  {
    float* vbuf = B_;
    int wb = pb*64;
    float nwv = nw[wb+lane], nbv = nb[wb+lane];
    for (int r = wid; r < 67; r += 4) {
      float v = 0.f;
      bool valid = (r >= 3) || (t0 != 0);
      if (valid) {
        int tok = tok0 - 3 + r;
        float hv = h[tok*64 + lane];
        float rr = (layer == 0) ? hv : hv + res_in[tok*64 + lane];
        if (r >= 3) res_out[tok*64 + lane] = rr;
        float sum = rr;
        #pragma unroll
        for (int o = 32; o > 0; o >>= 1) sum += __shfl_xor(sum, o);
        float mean = sum * (1.f/64.f);
        float df = rr - mean;
        float dv = df*df;
        #pragma unroll
        for (int o = 32; o > 0; o >>= 1) dv += __shfl_xor(dv, o);
        float inv = rsqrtf(dv*(1.f/64.f) + 1e-5f);
        v = df*inv*nwv + nbv;
      }
      vbuf[r*64 + lane] = v;
    }
  }
  __syncthreads();
  // ---- P1: in_proj: thread = output row (256 rows); x rows -> LDS, z rows -> global ----
  {
    const float* vbuf = B_;
    float* xr = A_;
    const float4* W4 = (const float4*)(in_w + pb*16384 + tid*64);
    float4 w[16];
    #pragma unroll
    for (int i = 0; i < 16; ++i) w[i] = W4[i];
    for (int t = 0; t < 67; ++t) {
      const float4* v4 = (const float4*)(vbuf + t*64);
      float a = 0.f;
      #pragma unroll
      for (int i = 0; i < 16; ++i) {
        float4 vv = v4[i];
        a += vv.x*w[i].x + vv.y*w[i].y + vv.z*w[i].z + vv.w*w[i].w;
      }
      if (tid < 128) xr[t*128 + tid] = a;
      else if (t >= 3) zb[(tok0 + t - 3)*128 + (tid - 128)] = a;
    }
  }
  __syncthreads();
  // ---- P2: causal conv + silu -> xs[64][132] ----
  {
    const float* xr = A_;
    float* xs = B_;
    int d = tid & 127, half = tid >> 7;
    float4 cwv = ((const float4*)(conv_w + (pb*128 + d)*4))[0];
    float cb = conv_b[pb*128 + d];
    for (int i = 0; i < 32; ++i) {
      int tl = i*2 + half;
      float acc = cb + xr[tl*128 + d]*cwv.x + xr[(tl+1)*128 + d]*cwv.y
                     + xr[(tl+2)*128 + d]*cwv.z + xr[(tl+3)*128 + d]*cwv.w;
      float xv = acc / (1.f + __expf(-acc));
      xs[tl*132 + d] = xv;
    }
  }
  __syncthreads();
  // ---- P3a: x_proj partials: thread = (K-quarter jg, token tl) ----
  {
    const float* xs = B_;
    float* dblp = A_;               // [jg][36][64]
    int jg = tid >> 6, tl = tid & 63;
    const float4* xq = (const float4*)(xs + tl*132 + jg*32);
    float4 xv[8];
    #pragma unroll
    for (int i = 0; i < 8; ++i) xv[i] = xq[i];
    const float* XW = xproj_w + pb*36*128 + jg*32;
    for (int j = 0; j < 36; ++j) {
      const float4* wv = (const float4*)(XW + j*128);
      float s = 0.f;
      #pragma unroll
      for (int k = 0; k < 8; ++k) {
        float4 ww = wv[k];
        s += xv[k].x*ww.x + xv[k].y*ww.y + xv[k].z*ww.z + xv[k].w*ww.w;
      }
      dblp[(jg*36 + j)*64 + tl] = s;
    }
  }
  __syncthreads();
  // ---- P3b: reduce quarters -> dbl[64][DBLS] ----
  {
    const float* dblp = A_;
    for (int i = tid; i < 2304; i += 256) {
      int j = i >> 6, tl = i & 63;
      float s = dblp[(0*36 + j)*64 + tl] + dblp[(1*36 + j)*64 + tl]
              + dblp[(2*36 + j)*64 + tl] + dblp[(3*36 + j)*64 + tl];
      D_[tl*DBLS + j] = s;
    }
  }
  __syncthreads();
  // ---- P4: dt (softplus) -> sdt[64][132]; Cg -> global ----
  {
    float* sdt = A_;
    int d = tid & 127, half = tid >> 7;
    float4 dwv = ((const float4*)(dt_w + (pb*128 + d)*4))[0];
    float dtbv = dt_b[pb*128 + d];
    for (int i = 0; i < 32; ++i) {
      int tl = i*2 + half;
      float dpre = dtbv + D_[tl*DBLS+0]*dwv.x + D_[tl*DBLS+1]*dwv.y
                        + D_[tl*DBLS+2]*dwv.z + D_[tl*DBLS+3]*dwv.w;
      float sp = fmaxf(dpre, 0.f) + log1pf(__expf(-fabsf(dpre)));
      sdt[tl*132 + d] = sp;
    }
    for (int i = tid; i < 1024; i += 256) {
      int tl = i >> 4, s = i & 15;
      Cg[(tok0 + tl)*16 + s] = D_[tl*DBLS + 20 + s];
    }
  }
  __syncthreads();
  // ---- P5: local scan (thread = (d, state-half)) ----
  {
    const float* sdt = A_;
    const float* xs = B_;
    int sd = tid >> 1, p = tid & 1, s0 = p*8;
    float ae[8];
    {
      const float4* A4 = (const float4*)(Ae + pb*2048 + sd*16 + s0);
      float4 a0 = A4[0], a1 = A4[1];
      ae[0]=a0.x; ae[1]=a0.y; ae[2]=a0.z; ae[3]=a0.w;
      ae[4]=a1.x; ae[5]=a1.y; ae[6]=a1.z; ae[7]=a1.w;
    }
    float Dv = Dp[pb*128 + sd];
    float hs[8] = {0,0,0,0,0,0,0,0};
    float cum = 0.f;
    for (int t = 0; t < CHUNK; ++t) {
      float dtv = sdt[t*132 + sd];
      float xv  = xs[t*132 + sd];
      cum += dtv;
      float dtx = dtv*xv;
      float acc = 0.f;
      #pragma unroll
      for (int s = 0; s < 8; ++s) {
        float Bv = D_[t*DBLS + 4 + s0 + s];
        float Cv = D_[t*DBLS + 20 + s0 + s];
        float dA = exp2f(dtv*ae[s]);
        hs[s] = dA*hs[s] + dtx*Bv;
        acc += hs[s]*Cv;
      }
      acc += __shfl_xor(acc, 1);
      if (p == 0) {
        int tok = tok0 + t;
        ylocal[tok*128 + sd] = acc + xv*Dv;
        cumdt[tok*128 + sd] = cum;
      }
    }
    int base = blockIdx.x*2048 + sd*16 + s0;
    #pragma unroll
    for (int s = 0; s < 8; ++s) { hend[base+s] = hs[s]; Pst[base+s] = exp2f(ae[s]*cum); }
  }
}

// ---------------- kC: prefix across chunks (Sinit in place over Pst) ----------------
__global__ __launch_bounds__(256) void kC(const float* __restrict__ hend, float* __restrict__ Pst) {
  int db = blockIdx.x >> 3;       // 128 blocks: db*8 + slice
  int e  = (blockIdx.x & 7)*256 + threadIdx.x;
  float init = 0.f;
  #pragma unroll 4
  for (int c = 0; c < NCH; ++c) {
    int base = (db*NCH + c)*2048 + e;
    float pz = Pst[base];
    float he = hend[base];
    Pst[base] = init;
    init = pz*init + he;
  }
}

// ============ kD: correction + gate -> LDS, then out-proj (K-quartered) ============
__global__ __launch_bounds__(256) void kD(
    const float* __restrict__ ylocal, const float* __restrict__ cumdt,
    const float* __restrict__ zb, const float* __restrict__ Cg,
    const float* __restrict__ Sinit, const float* __restrict__ Ae,
    const float* __restrict__ out_w, float* __restrict__ hout, int layer)
{
  __shared__ __align__(16) float ys[64*148];   // swizzled: col = (d>>5)*36 + (d&31)
  int tid = threadIdx.x;
  int tok0 = blockIdx.x * 64;
  int dir = tok0 >> 14;
  int pb = dir*4 + layer;
  // ---- phase 1: y = (ylocal + sum_s exp2(ae*cum)*Si*C) * silu(z) ----
  {
    int d = tid & 127, tg = tid >> 7;
    float ae[16], Si[16];
    {
      const float4* A4 = (const float4*)(Ae + pb*2048 + d*16);
      const float4* S4 = (const float4*)(Sinit + blockIdx.x*2048 + d*16);
      #pragma unroll
      for (int q = 0; q < 4; ++q) {
        float4 a = A4[q], s = S4[q];
        ae[q*4+0]=a.x; ae[q*4+1]=a.y; ae[q*4+2]=a.z; ae[q*4+3]=a.w;
        Si[q*4+0]=s.x; Si[q*4+1]=s.y; Si[q*4+2]=s.z; Si[q*4+3]=s.w;
      }
    }
    int col = (d >> 5)*36 + (d & 31);
    for (int i = 0; i < 32; ++i) {
      int tl = i*2 + tg;
      int tok = tok0 + tl;
      float cum = cumdt[tok*128 + d];
      const float4* C4 = (const float4*)(Cg + tok*16);
      float corr = 0.f;
      #pragma unroll
      for (int q = 0; q < 4; ++q) {
        float4 cc = C4[q];
        corr += exp2f(ae[q*4+0]*cum)*Si[q*4+0]*cc.x;
        corr += exp2f(ae[q*4+1]*cum)*Si[q*4+1]*cc.y;
        corr += exp2f(ae[q*4+2]*cum)*Si[q*4+2]*cc.z;
        corr += exp2f(ae[q*4+3]*cum)*Si[q*4+3]*cc.w;
      }
      float yl = ylocal[tok*128 + d];
      float zv = zb[tok*128 + d];
      ys[tl*148 + col] = (yl + corr) * (zv / (1.f + __expf(-zv)));
    }
  }
  __syncthreads();
  // ---- phase 2: out-proj: lane = (q, jj), j = wid*16+jj; K-quarter in regs ----
  {
    int lane = tid & 63, wid = tid >> 6;
    int jj = lane & 15, q = lane >> 4;
    int j = wid*16 + jj;
    const float4* W4 = (const float4*)(out_w + pb*8192 + j*128 + q*32);
    float4 w[8];
    #pragma unroll
    for (int i = 0; i < 8; ++i) w[i] = W4[i];
    for (int t = 0; t < 64; ++t) {
      const float4* yv = (const float4*)(ys + t*148 + q*36);
      float a = 0.f;
      #pragma unroll
      for (int i = 0; i < 8; ++i) {
        float4 vv = yv[i];
        a += vv.x*w[i].x + vv.y*w[i].y + vv.z*w[i].z + vv.w*w[i].w;
      }
      a += __shfl_xor(a, 16);
      a += __shfl_xor(a, 32);
      if (q == 0) hout[(tok0 + t)*64 + j] = a;
    }
  }
}

// ---------------- k5: final residual add + LN + pool logits ----------------
__global__ void k5(const float* __restrict__ h, const float* __restrict__ res,
                   float* __restrict__ hfin, float* __restrict__ logits,
                   const float* __restrict__ nfw, const float* __restrict__ nfb,
                   const float* __restrict__ fpw, const float* __restrict__ fpb,
                   const float* __restrict__ bpw, const float* __restrict__ bpb) {
  int wid = threadIdx.x >> 6, lane = threadIdx.x & 63;
  int tok = blockIdx.x*4 + wid;
  int dir = tok >> 14;
  float r = h[tok*64 + lane] + res[tok*64 + lane];
  float sum = r;
  #pragma unroll
  for (int o = 32; o > 0; o >>= 1) sum += __shfl_xor(sum, o);
  float mean = sum * (1.f/64.f);
  float df = r - mean;
  float dv = df*df;
  #pragma unroll
  for (int o = 32; o > 0; o >>= 1) dv += __shfl_xor(dv, o);
  float inv = rsqrtf(dv*(1.f/64.f) + 1e-5f);
  float v = df*inv*nfw[lane] + nfb[lane];
  hfin[tok*64 + lane] = v;
  float lg = v * (dir ? bpw[lane] : fpw[lane]);
  #pragma unroll
  for (int o = 32; o > 0; o >>= 1) lg += __shfl_xor(lg, o);
  if (lane == 0) logits[tok] = lg + (dir ? bpb[0] : fpb[0]);
}

// ---------------- k6a: softmax stats per sequence ----------------
__global__ void k6a(const float* __restrict__ logits, float* __restrict__ stats) {
  int blk = blockIdx.x;           // 16
  int tid = threadIdx.x;          // 256
  int tok0 = blk*T;
  __shared__ float red[256];
  float mx = -1e30f;
  for (int t = tid; t < T; t += 256) mx = fmaxf(mx, logits[tok0 + t]);
  red[tid] = mx; __syncthreads();
  for (int o = 128; o > 0; o >>= 1) { if (tid < o) red[tid] = fmaxf(red[tid], red[tid+o]); __syncthreads(); }
  mx = red[0]; __syncthreads();
  float sm = 0.f;
  for (int t = tid; t < T; t += 256) sm += __expf(logits[tok0 + t] - mx);
  red[tid] = sm; __syncthreads();
  for (int o = 128; o > 0; o >>= 1) { if (tid < o) red[tid] += red[tid+o]; __syncthreads(); }
  if (tid == 0) { stats[blk] = mx; stats[16+blk] = 1.f/red[0]; }
}

// ---------------- k6b: sliced weighted pool ----------------
__global__ void k6b(const float* __restrict__ hfin, const float* __restrict__ logits,
                    const float* __restrict__ stats, float* __restrict__ pf) {
  int blk = blockIdx.x;            // 128 = seq*8 + slice
  int seq = blk >> 3, slice = blk & 7;
  int tid = threadIdx.x;
  int w = tid >> 6, m = tid & 63;
  float mx = stats[seq], inv = stats[16+seq];
  int tok0 = seq*T + slice*256;
  float pacc = 0.f;
  for (int t = w; t < 256; t += 4) {
    float a = __expf(logits[tok0 + t] - mx)*inv;
    pacc += a * hfin[(tok0 + t)*64 + m];
  }
  __shared__ float red[256];
  red[tid] = pacc; __syncthreads();
  if (w == 0) pf[(seq*64 + m)*8 + slice] = red[m] + red[64+m] + red[128+m] + red[192+m];
}

// ---------------- k6c: reduce slices ----------------
__global__ void k6c(const float* __restrict__ pf, float* __restrict__ pooled) {
  int i = blockIdx.x*256 + threadIdx.x;   // 1024
  if (i >= 1024) return;
  const float4* p4 = (const float4*)(pf + i*8);
  float4 a = p4[0], b = p4[1];
  pooled[i] = a.x+a.y+a.z+a.w+b.x+b.y+b.z+b.w;
}

// ---------------- k7: head ----------------
__global__ void k7(const float* __restrict__ pooled, float* __restrict__ out,
                   const float* __restrict__ llw, const float* __restrict__ llb) {
  int idx = blockIdx.x*256 + threadIdx.x;
  if (idx >= 512) return;
  int b = idx >> 6, j = idx & 63;
  float a = llb[j];
  for (int d = 0; d < 64; ++d) {
    a += pooled[b*64 + d]       * llw[j*128 + d];
    a += pooled[(8+b)*64 + d]   * llw[j*128 + 64 + d];
  }
  out[idx] = a;
}

extern "C" void kernel_launch(void* const* d_in, const int* in_sizes, int n_in,
                              void* d_out, int out_size, void* d_ws, size_t ws_size,
                              hipStream_t stream) {
  const float* x      = (const float*)d_in[0];
  const float* in_w   = (const float*)d_in[1];
  const float* conv_w = (const float*)d_in[2];
  const float* conv_b = (const float*)d_in[3];
  const float* xproj_w= (const float*)d_in[4];
  const float* dt_w   = (const float*)d_in[5];
  const float* dt_b   = (const float*)d_in[6];
  const float* A_log  = (const float*)d_in[7];
  const float* Dp     = (const float*)d_in[8];
  const float* out_w  = (const float*)d_in[9];
  const float* nw     = (const float*)d_in[10];
  const float* nb     = (const float*)d_in[11];
  const float* nfw    = (const float*)d_in[12];
  const float* nfb    = (const float*)d_in[13];
  const float* fpw    = (const float*)d_in[14];
  const float* fpb    = (const float*)d_in[15];
  const float* bpw    = (const float*)d_in[16];
  const float* bpb    = (const float*)d_in[17];
  const float* llw    = (const float*)d_in[18];
  const float* llb    = (const float*)d_in[19];
  float* ws  = (float*)d_ws;
  float* h      = ws;                    // 2M
  float* resA   = ws + 2097152;          // 2M
  float* resB   = ws + 4194304;          // 2M
  float* zb     = ws + 6291456;          // 4M
  float* ylocal = ws + 10485760;         // 4M
  float* cumdt  = ws + 14680064;         // 4M (reused as hfin in tail)
  float* Cg     = ws + 18874368;         // 512K
  float* hend   = ws + 19398656;         // 1M
  float* Pst    = ws + 20447232;         // 1M (Sinit in place)
  float* logits = ws + 21495808;         // 32K
  float* pf     = ws + 21528576;         // 8K
  float* pooled = ws + 21536768;         // 1K
  float* stats  = ws + 21537792;         // 32
  float* AeBuf  = ws + 21537824;         // 16K
  float* out    = (float*)d_out;

  k_prep<<<dim3(8192), dim3(256), 0, stream>>>(x, h);
  kAe   <<<dim3(64),   dim3(256), 0, stream>>>(A_log, AeBuf);
  for (int layer = 0; layer < 4; ++layer) {
    float* rin  = (layer & 1) ? resB : resA;
    float* rout = (layer & 1) ? resA : resB;
    if (layer == 0) { rin = resA; rout = resA; }
    else if (layer == 1) { rin = resA; rout = resB; }
    else if (layer == 2) { rin = resB; rout = resA; }
    else { rin = resA; rout = resB; }
    kA<<<dim3(512), dim3(256), 0, stream>>>(h, rin, rout, zb, ylocal, cumdt, Cg, hend, Pst,
                                            in_w, nw, nb, conv_w, conv_b, xproj_w, dt_w, dt_b,
                                            AeBuf, Dp, layer);
    kC<<<dim3(128), dim3(256), 0, stream>>>(hend, Pst);
    kD<<<dim3(512), dim3(256), 0, stream>>>(ylocal, cumdt, zb, Cg, Pst, AeBuf, out_w, h, layer);
  }
  k5 <<<dim3(8192), dim3(256), 0, stream>>>(h, resB, cumdt, logits, nfw, nfb, fpw, fpb, bpw, bpb);
  k6a<<<dim3(16),   dim3(256), 0, stream>>>(logits, stats);
  k6b<<<dim3(128),  dim3(256), 0, stream>>>(cumdt, logits, stats, pf);
  k6c<<<dim3(4),    dim3(256), 0, stream>>>(pf, pooled);
  k7 <<<dim3(2),    dim3(256), 0, stream>>>(pooled, out, llw, llb);
}

// Round 5
// 644.596 us; speedup vs baseline: 4.7413x; 1.0756x over previous
//
#include <hip/hip_runtime.h>
#include <math.h>

#define T 2048
#define NTOK 32768   // 2 dirs * 8 batch * 2048
#define CHUNK 64
#define NCH 32
#define LOG2E 1.4426950408889634f
#define DBLS 44      // padded stride for dbl[64][44]; 44*4B=176B, 16B-aligned

// ---------------- prep: x (8,64,2048) -> h[dir,b,t,m], backward flipped ----------------
__global__ void k_prep(const float* __restrict__ x, float* __restrict__ h) {
  int idx = blockIdx.x*256 + threadIdx.x;       // NTOK*64
  int m   = idx & 63;
  int tok = idx >> 6;
  int t   = tok & (T-1);
  int b   = (tok >> 11) & 7;
  int dir = tok >> 14;
  int tt  = dir ? (T-1-t) : t;
  h[idx] = x[(b*64 + m)*2048 + tt];
}

// ---------------- kAe: Ae[pb][d][s] = -exp(A_log)*log2e ----------------
__global__ void kAe(const float* __restrict__ A_log, float* __restrict__ Ae) {
  int i = blockIdx.x*256 + threadIdx.x;   // 16384
  Ae[i] = -__expf(A_log[i]) * LOG2E;
}

// ============ kA: LN + in_proj + conv + x_proj + dt + local chunk scan ============
// block = 64 tokens = one chunk. LDS-resident pipeline.
__global__ __launch_bounds__(256, 2) void kA(
    const float* __restrict__ h, const float* __restrict__ res_in, float* __restrict__ res_out,
    float* __restrict__ zb, float* __restrict__ ylocal, float* __restrict__ cumdt,
    float* __restrict__ Cg, float* __restrict__ hend, float* __restrict__ Pst,
    const float* __restrict__ in_w, const float* __restrict__ nw, const float* __restrict__ nb,
    const float* __restrict__ conv_w, const float* __restrict__ conv_b,
    const float* __restrict__ xproj_w, const float* __restrict__ dt_w, const float* __restrict__ dt_b,
    const float* __restrict__ Ae, const float* __restrict__ Dp, int layer)
{
  __shared__ __align__(16) float A_[8576];  // xr[67][128] -> dblp[2][36][64] -> sdt[64][132]
  __shared__ __align__(16) float B_[8448];  // vbuf[67][64] -> xs[64][132]
  __shared__ __align__(16) float D_[64*DBLS];
  int tid = threadIdx.x;
  int tok0 = blockIdx.x * 64;
  int t0 = tok0 & (T-1);
  int dir = tok0 >> 14;
  int pb = dir*4 + layer;
  int wid = tid >> 6, lane = tid & 63;

  // ---- P0: residual + LN for rows 0..66 (row r <-> token tok0-3+r) ----
  {
    float* vbuf = B_;
    int wb = pb*64;
    float nwv = nw[wb+lane], nbv = nb[wb+lane];
    for (int r = wid; r < 67; r += 4) {
      float v = 0.f;
      bool valid = (r >= 3) || (t0 != 0);
      if (valid) {
        int tok = tok0 - 3 + r;
        float hv = h[tok*64 + lane];
        float rr = (layer == 0) ? hv : hv + res_in[tok*64 + lane];
        if (r >= 3) res_out[tok*64 + lane] = rr;
        float sum = rr;
        #pragma unroll
        for (int o = 32; o > 0; o >>= 1) sum += __shfl_xor(sum, o);
        float mean = sum * (1.f/64.f);
        float df = rr - mean;
        float dv = df*df;
        #pragma unroll
        for (int o = 32; o > 0; o >>= 1) dv += __shfl_xor(dv, o);
        float inv = rsqrtf(dv*(1.f/64.f) + 1e-5f);
        v = df*inv*nwv + nbv;
      }
      vbuf[r*64 + lane] = v;
    }
  }
  __syncthreads();
  // ---- P1: in_proj, R=2 register tiling: thread owns rows {2j2, 2j2+1}, half the tokens ----
  {
    const float* vbuf = B_;
    float* xr = A_;
    int j2 = tid & 127, th = tid >> 7;
    int r0 = j2*2;
    const float4* W4 = (const float4*)(in_w + pb*16384 + r0*64);
    float4 wa[16], wb16[16];
    #pragma unroll
    for (int i = 0; i < 16; ++i) wa[i] = W4[i];
    #pragma unroll
    for (int i = 0; i < 16; ++i) wb16[i] = W4[16+i];
    int tbeg = th ? 34 : 0, tend = th ? 67 : 34;
    for (int t = tbeg; t < tend; ++t) {
      const float4* v4 = (const float4*)(vbuf + t*64);
      float a0 = 0.f, a1 = 0.f;
      #pragma unroll
      for (int i = 0; i < 16; ++i) {
        float4 vv = v4[i];
        a0 += vv.x*wa[i].x + vv.y*wa[i].y + vv.z*wa[i].z + vv.w*wa[i].w;
        a1 += vv.x*wb16[i].x + vv.y*wb16[i].y + vv.z*wb16[i].z + vv.w*wb16[i].w;
      }
      if (j2 < 64) {
        *(float2*)(xr + t*128 + r0) = make_float2(a0, a1);
      } else if (t >= 3) {
        *(float2*)(zb + (size_t)(tok0 + t - 3)*128 + (r0 - 128)) = make_float2(a0, a1);
      }
    }
  }
  __syncthreads();
  // ---- P2: causal conv + silu -> xs[64][132] ----
  {
    const float* xr = A_;
    float* xs = B_;
    int d = tid & 127, half = tid >> 7;
    float4 cwv = ((const float4*)(conv_w + (pb*128 + d)*4))[0];
    float cb = conv_b[pb*128 + d];
    for (int i = 0; i < 32; ++i) {
      int tl = i*2 + half;
      float acc = cb + xr[tl*128 + d]*cwv.x + xr[(tl+1)*128 + d]*cwv.y
                     + xr[(tl+2)*128 + d]*cwv.z + xr[(tl+3)*128 + d]*cwv.w;
      float xv = acc / (1.f + __expf(-acc));
      xs[tl*132 + d] = xv;
    }
  }
  __syncthreads();
  // ---- P3a: x_proj partials: K-halves; lane = token, wave picks (K-half, j-range) ----
  {
    const float* xs = B_;
    float* dblp = A_;               // [2][36][64]
    int tl = tid & 63, jsub = (tid >> 6) & 1, jh = tid >> 7;
    const float4* xq = (const float4*)(xs + tl*132 + jh*64);
    float4 xv[16];
    #pragma unroll
    for (int i = 0; i < 16; ++i) xv[i] = xq[i];
    const float* XW = xproj_w + pb*36*128 + jh*64;
    for (int j = jsub*18; j < jsub*18 + 18; ++j) {
      const float4* wv = (const float4*)(XW + j*128);
      float s = 0.f;
      #pragma unroll
      for (int k = 0; k < 16; ++k) {
        float4 ww = wv[k];
        s += xv[k].x*ww.x + xv[k].y*ww.y + xv[k].z*ww.z + xv[k].w*ww.w;
      }
      dblp[(jh*36 + j)*64 + tl] = s;
    }
  }
  __syncthreads();
  // ---- P3b: reduce halves -> D_[64][DBLS] ----
  {
    const float* dblp = A_;
    for (int i = tid; i < 2304; i += 256) {
      int j = i >> 6, tl = i & 63;
      D_[tl*DBLS + j] = dblp[j*64 + tl] + dblp[(36 + j)*64 + tl];
    }
  }
  __syncthreads();
  // ---- P4: dt (softplus) -> sdt[64][132]; Cg -> global ----
  {
    float* sdt = A_;
    int d = tid & 127, half = tid >> 7;
    float4 dwv = ((const float4*)(dt_w + (pb*128 + d)*4))[0];
    float dtbv = dt_b[pb*128 + d];
    for (int i = 0; i < 32; ++i) {
      int tl = i*2 + half;
      float dpre = dtbv + D_[tl*DBLS+0]*dwv.x + D_[tl*DBLS+1]*dwv.y
                        + D_[tl*DBLS+2]*dwv.z + D_[tl*DBLS+3]*dwv.w;
      float sp = fmaxf(dpre, 0.f) + log1pf(__expf(-fabsf(dpre)));
      sdt[tl*132 + d] = sp;
    }
    for (int i = tid; i < 1024; i += 256) {
      int tl = i >> 4, s = i & 15;
      Cg[(tok0 + tl)*16 + s] = D_[tl*DBLS + 20 + s];
    }
  }
  __syncthreads();
  // ---- P5: local scan (thread = (d, state-half)); B/C as float4 ----
  {
    const float* sdt = A_;
    const float* xs = B_;
    int sd = tid >> 1, p = tid & 1, s0 = p*8;
    float ae[8];
    {
      const float4* A4 = (const float4*)(Ae + pb*2048 + sd*16 + s0);
      float4 a0 = A4[0], a1 = A4[1];
      ae[0]=a0.x; ae[1]=a0.y; ae[2]=a0.z; ae[3]=a0.w;
      ae[4]=a1.x; ae[5]=a1.y; ae[6]=a1.z; ae[7]=a1.w;
    }
    float Dv = Dp[pb*128 + sd];
    float hs[8] = {0,0,0,0,0,0,0,0};
    float cum = 0.f;
    for (int t = 0; t < CHUNK; ++t) {
      float dtv = sdt[t*132 + sd];
      float xv  = xs[t*132 + sd];
      cum += dtv;
      float dtx = dtv*xv;
      const float4* B4 = (const float4*)(D_ + t*DBLS + 4 + s0);
      const float4* C4 = (const float4*)(D_ + t*DBLS + 20 + s0);
      float4 b0=B4[0], b1=B4[1], cc0=C4[0], cc1=C4[1];
      float bv[8] = {b0.x,b0.y,b0.z,b0.w,b1.x,b1.y,b1.z,b1.w};
      float cv[8] = {cc0.x,cc0.y,cc0.z,cc0.w,cc1.x,cc1.y,cc1.z,cc1.w};
      float acc = 0.f;
      #pragma unroll
      for (int s = 0; s < 8; ++s) {
        float dA = exp2f(dtv*ae[s]);
        hs[s] = dA*hs[s] + dtx*bv[s];
        acc += hs[s]*cv[s];
      }
      acc += __shfl_xor(acc, 1);
      if (p == 0) {
        int tok = tok0 + t;
        ylocal[tok*128 + sd] = acc + xv*Dv;
        cumdt[tok*128 + sd] = cum;
      }
    }
    int base = blockIdx.x*2048 + sd*16 + s0;
    #pragma unroll
    for (int s = 0; s < 8; ++s) { hend[base+s] = hs[s]; Pst[base+s] = exp2f(ae[s]*cum); }
  }
}

// ---------------- kC: prefix across chunks (Sinit in place over Pst) ----------------
__global__ __launch_bounds__(256) void kC(const float* __restrict__ hend, float* __restrict__ Pst) {
  int db = blockIdx.x >> 3;       // 128 blocks: db*8 + slice
  int e  = (blockIdx.x & 7)*256 + threadIdx.x;
  float init = 0.f;
  #pragma unroll 4
  for (int c = 0; c < NCH; ++c) {
    int base = (db*NCH + c)*2048 + e;
    float pz = Pst[base];
    float he = hend[base];
    Pst[base] = init;
    init = pz*init + he;
  }
}

// ============ kD: correction + gate -> LDS, then out-proj (R=2 tiled) ============
__global__ __launch_bounds__(256) void kD(
    const float* __restrict__ ylocal, const float* __restrict__ cumdt,
    const float* __restrict__ zb, const float* __restrict__ Cg,
    const float* __restrict__ Sinit, const float* __restrict__ Ae,
    const float* __restrict__ out_w, float* __restrict__ hout, int layer)
{
  __shared__ __align__(16) float ys[64*148];   // swizzled: col = (d>>5)*36 + (d&31)
  int tid = threadIdx.x;
  int tok0 = blockIdx.x * 64;
  int dir = tok0 >> 14;
  int pb = dir*4 + layer;
  // ---- phase 1: y = (ylocal + sum_s exp2(ae*cum)*Si*C) * silu(z) ----
  {
    int d = tid & 127, tg = tid >> 7;
    float ae[16], Si[16];
    {
      const float4* A4 = (const float4*)(Ae + pb*2048 + d*16);
      const float4* S4 = (const float4*)(Sinit + blockIdx.x*2048 + d*16);
      #pragma unroll
      for (int q = 0; q < 4; ++q) {
        float4 a = A4[q], s = S4[q];
        ae[q*4+0]=a.x; ae[q*4+1]=a.y; ae[q*4+2]=a.z; ae[q*4+3]=a.w;
        Si[q*4+0]=s.x; Si[q*4+1]=s.y; Si[q*4+2]=s.z; Si[q*4+3]=s.w;
      }
    }
    int col = (d >> 5)*36 + (d & 31);
    for (int i = 0; i < 32; ++i) {
      int tl = i*2 + tg;
      int tok = tok0 + tl;
      float cum = cumdt[tok*128 + d];
      const float4* C4 = (const float4*)(Cg + tok*16);
      float corr = 0.f;
      #pragma unroll
      for (int q = 0; q < 4; ++q) {
        float4 cc = C4[q];
        corr += exp2f(ae[q*4+0]*cum)*Si[q*4+0]*cc.x;
        corr += exp2f(ae[q*4+1]*cum)*Si[q*4+1]*cc.y;
        corr += exp2f(ae[q*4+2]*cum)*Si[q*4+2]*cc.z;
        corr += exp2f(ae[q*4+3]*cum)*Si[q*4+3]*cc.w;
      }
      float yl = ylocal[tok*128 + d];
      float zv = zb[tok*128 + d];
      ys[tl*148 + col] = (yl + corr) * (zv / (1.f + __expf(-zv)));
    }
  }
  __syncthreads();
  // ---- phase 2: out-proj; lane = (q, jj); wave = (row-half, token-half); 2 rows/lane ----
  {
    int lane = tid & 63, wid = tid >> 6;
    int q = lane >> 4, jj = lane & 15;
    int rh = wid >> 1, th = wid & 1;
    int j0 = rh*32 + jj;                 // rows j0 and j0+16
    const float4* W4a = (const float4*)(out_w + pb*8192 + j0*128 + q*32);
    const float4* W4b = (const float4*)(out_w + pb*8192 + (j0+16)*128 + q*32);
    float4 wa[8], wb8[8];
    #pragma unroll
    for (int i = 0; i < 8; ++i) wa[i] = W4a[i];
    #pragma unroll
    for (int i = 0; i < 8; ++i) wb8[i] = W4b[i];
    for (int t = th*32; t < th*32 + 32; ++t) {
      const float4* yv = (const float4*)(ys + t*148 + q*36);
      float a0 = 0.f, a1 = 0.f;
      #pragma unroll
      for (int i = 0; i < 8; ++i) {
        float4 vv = yv[i];
        a0 += vv.x*wa[i].x + vv.y*wa[i].y + vv.z*wa[i].z + vv.w*wa[i].w;
        a1 += vv.x*wb8[i].x + vv.y*wb8[i].y + vv.z*wb8[i].z + vv.w*wb8[i].w;
      }
      a0 += __shfl_xor(a0, 16); a0 += __shfl_xor(a0, 32);
      a1 += __shfl_xor(a1, 16); a1 += __shfl_xor(a1, 32);
      if (q == 0) {
        hout[(tok0 + t)*64 + j0]      = a0;
        hout[(tok0 + t)*64 + j0 + 16] = a1;
      }
    }
  }
}

// ---------------- k5: final residual add + LN + pool logits ----------------
__global__ void k5(const float* __restrict__ h, const float* __restrict__ res,
                   float* __restrict__ hfin, float* __restrict__ logits,
                   const float* __restrict__ nfw, const float* __restrict__ nfb,
                   const float* __restrict__ fpw, const float* __restrict__ fpb,
                   const float* __restrict__ bpw, const float* __restrict__ bpb) {
  int wid = threadIdx.x >> 6, lane = threadIdx.x & 63;
  int tok = blockIdx.x*4 + wid;
  int dir = tok >> 14;
  float r = h[tok*64 + lane] + res[tok*64 + lane];
  float sum = r;
  #pragma unroll
  for (int o = 32; o > 0; o >>= 1) sum += __shfl_xor(sum, o);
  float mean = sum * (1.f/64.f);
  float df = r - mean;
  float dv = df*df;
  #pragma unroll
  for (int o = 32; o > 0; o >>= 1) dv += __shfl_xor(dv, o);
  float inv = rsqrtf(dv*(1.f/64.f) + 1e-5f);
  float v = df*inv*nfw[lane] + nfb[lane];
  hfin[tok*64 + lane] = v;
  float lg = v * (dir ? bpw[lane] : fpw[lane]);
  #pragma unroll
  for (int o = 32; o > 0; o >>= 1) lg += __shfl_xor(lg, o);
  if (lane == 0) logits[tok] = lg + (dir ? bpb[0] : fpb[0]);
}

// ---------------- k6a: softmax stats per sequence ----------------
__global__ void k6a(const float* __restrict__ logits, float* __restrict__ stats) {
  int blk = blockIdx.x;           // 16
  int tid = threadIdx.x;          // 256
  int tok0 = blk*T;
  __shared__ float red[256];
  float mx = -1e30f;
  for (int t = tid; t < T; t += 256) mx = fmaxf(mx, logits[tok0 + t]);
  red[tid] = mx; __syncthreads();
  for (int o = 128; o > 0; o >>= 1) { if (tid < o) red[tid] = fmaxf(red[tid], red[tid+o]); __syncthreads(); }
  mx = red[0]; __syncthreads();
  float sm = 0.f;
  for (int t = tid; t < T; t += 256) sm += __expf(logits[tok0 + t] - mx);
  red[tid] = sm; __syncthreads();
  for (int o = 128; o > 0; o >>= 1) { if (tid < o) red[tid] += red[tid+o]; __syncthreads(); }
  if (tid == 0) { stats[blk] = mx; stats[16+blk] = 1.f/red[0]; }
}

// ---------------- k6b: sliced weighted pool ----------------
__global__ void k6b(const float* __restrict__ hfin, const float* __restrict__ logits,
                    const float* __restrict__ stats, float* __restrict__ pf) {
  int blk = blockIdx.x;            // 128 = seq*8 + slice
  int seq = blk >> 3, slice = blk & 7;
  int tid = threadIdx.x;
  int w = tid >> 6, m = tid & 63;
  float mx = stats[seq], inv = stats[16+seq];
  int tok0 = seq*T + slice*256;
  float pacc = 0.f;
  for (int t = w; t < 256; t += 4) {
    float a = __expf(logits[tok0 + t] - mx)*inv;
    pacc += a * hfin[(tok0 + t)*64 + m];
  }
  __shared__ float red[256];
  red[tid] = pacc; __syncthreads();
  if (w == 0) pf[(seq*64 + m)*8 + slice] = red[m] + red[64+m] + red[128+m] + red[192+m];
}

// ---------------- k6c: reduce slices ----------------
__global__ void k6c(const float* __restrict__ pf, float* __restrict__ pooled) {
  int i = blockIdx.x*256 + threadIdx.x;   // 1024
  if (i >= 1024) return;
  const float4* p4 = (const float4*)(pf + i*8);
  float4 a = p4[0], b = p4[1];
  pooled[i] = a.x+a.y+a.z+a.w+b.x+b.y+b.z+b.w;
}

// ---------------- k7: head ----------------
__global__ void k7(const float* __restrict__ pooled, float* __restrict__ out,
                   const float* __restrict__ llw, const float* __restrict__ llb) {
  int idx = blockIdx.x*256 + threadIdx.x;
  if (idx >= 512) return;
  int b = idx >> 6, j = idx & 63;
  float a = llb[j];
  for (int d = 0; d < 64; ++d) {
    a += pooled[b*64 + d]       * llw[j*128 + d];
    a += pooled[(8+b)*64 + d]   * llw[j*128 + 64 + d];
  }
  out[idx] = a;
}

extern "C" void kernel_launch(void* const* d_in, const int* in_sizes, int n_in,
                              void* d_out, int out_size, void* d_ws, size_t ws_size,
                              hipStream_t stream) {
  const float* x      = (const float*)d_in[0];
  const float* in_w   = (const float*)d_in[1];
  const float* conv_w = (const float*)d_in[2];
  const float* conv_b = (const float*)d_in[3];
  const float* xproj_w= (const float*)d_in[4];
  const float* dt_w   = (const float*)d_in[5];
  const float* dt_b   = (const float*)d_in[6];
  const float* A_log  = (const float*)d_in[7];
  const float* Dp     = (const float*)d_in[8];
  const float* out_w  = (const float*)d_in[9];
  const float* nw     = (const float*)d_in[10];
  const float* nb     = (const float*)d_in[11];
  const float* nfw    = (const float*)d_in[12];
  const float* nfb    = (const float*)d_in[13];
  const float* fpw    = (const float*)d_in[14];
  const float* fpb    = (const float*)d_in[15];
  const float* bpw    = (const float*)d_in[16];
  const float* bpb    = (const float*)d_in[17];
  const float* llw    = (const float*)d_in[18];
  const float* llb    = (const float*)d_in[19];
  float* ws  = (float*)d_ws;
  float* h      = ws;                    // 2M
  float* resA   = ws + 2097152;          // 2M
  float* resB   = ws + 4194304;          // 2M
  float* zb     = ws + 6291456;          // 4M
  float* ylocal = ws + 10485760;         // 4M
  float* cumdt  = ws + 14680064;         // 4M (reused as hfin in tail)
  float* Cg     = ws + 18874368;         // 512K
  float* hend   = ws + 19398656;         // 1M
  float* Pst    = ws + 20447232;         // 1M (Sinit in place)
  float* logits = ws + 21495808;         // 32K
  float* pf     = ws + 21528576;         // 8K
  float* pooled = ws + 21536768;         // 1K
  float* stats  = ws + 21537792;         // 32
  float* AeBuf  = ws + 21537824;         // 16K
  float* out    = (float*)d_out;

  k_prep<<<dim3(8192), dim3(256), 0, stream>>>(x, h);
  kAe   <<<dim3(64),   dim3(256), 0, stream>>>(A_log, AeBuf);
  for (int layer = 0; layer < 4; ++layer) {
    float* rin, *rout;
    if (layer == 0) { rin = resA; rout = resA; }
    else if (layer == 1) { rin = resA; rout = resB; }
    else if (layer == 2) { rin = resB; rout = resA; }
    else { rin = resA; rout = resB; }
    kA<<<dim3(512), dim3(256), 0, stream>>>(h, rin, rout, zb, ylocal, cumdt, Cg, hend, Pst,
                                            in_w, nw, nb, conv_w, conv_b, xproj_w, dt_w, dt_b,
                                            AeBuf, Dp, layer);
    kC<<<dim3(128), dim3(256), 0, stream>>>(hend, Pst);
    kD<<<dim3(512), dim3(256), 0, stream>>>(ylocal, cumdt, zb, Cg, Pst, AeBuf, out_w, h, layer);
  }
  k5 <<<dim3(8192), dim3(256), 0, stream>>>(h, resB, cumdt, logits, nfw, nfb, fpw, fpb, bpw, bpb);
  k6a<<<dim3(16),   dim3(256), 0, stream>>>(logits, stats);
  k6b<<<dim3(128),  dim3(256), 0, stream>>>(cumdt, logits, stats, pf);
  k6c<<<dim3(4),    dim3(256), 0, stream>>>(pf, pooled);
  k7 <<<dim3(2),    dim3(256), 0, stream>>>(pooled, out, llw, llb);
}

// Round 6
// 487.916 us; speedup vs baseline: 6.2638x; 1.3211x over previous
//
#include <hip/hip_runtime.h>
#include <math.h>

#define T 2048
#define NTOK 32768   // 2 dirs * 8 batch * 2048
#define CH 32        // chunk = tokens per kA block
#define NCH 64       // chunks per sequence
#define ROWS 35      // CH + 3 halo
#define RP 48        // padded token rows for MFMA (3 tiles of 16)
#define XRS 132      // R1 stride in floats (528B: 16B-aligned, odd granule count)
#define DBLS 44      // D_ stride floats (176B: 16B-aligned)
#define LOG2E 1.4426950408889634f

typedef __attribute__((ext_vector_type(8))) short short8v;
typedef __attribute__((ext_vector_type(4))) float f32x4;

__device__ inline unsigned short bf16_rne(float f) {
  unsigned u = __float_as_uint(f);
  unsigned r = u + 0x7FFFu + ((u >> 16) & 1u);
  return (unsigned short)(r >> 16);
}
__device__ inline float bf16_to_f(unsigned short h) {
  return __uint_as_float(((unsigned)h) << 16);
}

// ---------------- prep: x (8,64,2048) -> h[dir,b,t,m], backward flipped ----------------
__global__ void k_prep(const float* __restrict__ x, float* __restrict__ h) {
  int idx = blockIdx.x*256 + threadIdx.x;       // NTOK*64
  int m   = idx & 63;
  int tok = idx >> 6;
  int t   = tok & (T-1);
  int b   = (tok >> 11) & 7;
  int dir = tok >> 14;
  int tt  = dir ? (T-1-t) : t;
  h[idx] = x[(b*64 + m)*2048 + tt];
}

// ---------------- kAe: Ae[pb][d][s] = -exp(A_log)*log2e ----------------
__global__ void kAe(const float* __restrict__ A_log, float* __restrict__ Ae) {
  int i = blockIdx.x*256 + threadIdx.x;   // 16384
  Ae[i] = -__expf(A_log[i]) * LOG2E;
}

// ---------------- kSplit: bf16 hi/lo split of in_w and xproj_w (padded to 48 rows) ----------------
__global__ void kSplit(const float* __restrict__ in_w, const float* __restrict__ xproj_w,
                       unsigned short* __restrict__ iwh, unsigned short* __restrict__ iwl,
                       unsigned short* __restrict__ xph, unsigned short* __restrict__ xpl) {
  int i = blockIdx.x*256 + threadIdx.x;   // 512 blocks = 131072
  if (i < 131072) {
    float f = in_w[i];
    unsigned short hb = bf16_rne(f);
    iwh[i] = hb;
    iwl[i] = bf16_rne(f - bf16_to_f(hb));
  }
  if (i < 49152) {                         // 8 * 48 * 128
    int k = i & 127;
    int j = (i >> 7) % 48;
    int pb = i / 6144;
    float f = (j < 36) ? xproj_w[(pb*36 + j)*128 + k] : 0.f;
    unsigned short hb = bf16_rne(f);
    xph[i] = hb;
    xpl[i] = bf16_rne(f - bf16_to_f(hb));
  }
}

// ============ kA: LN + in_proj(MFMA) + conv + x_proj(MFMA) + fused-dt chunk scan ============
// block = 32 tokens = one chunk.
__global__ __launch_bounds__(256) void kA(
    const float* __restrict__ h, const float* __restrict__ res_in, float* __restrict__ res_out,
    float* __restrict__ zb, float* __restrict__ ylocal, float* __restrict__ cumdt,
    float* __restrict__ Cg, float* __restrict__ hend, float* __restrict__ Pst,
    const unsigned short* __restrict__ iwh, const unsigned short* __restrict__ iwl,
    const unsigned short* __restrict__ xph, const unsigned short* __restrict__ xpl,
    const float* __restrict__ nw, const float* __restrict__ nb,
    const float* __restrict__ conv_w, const float* __restrict__ conv_b,
    const float* __restrict__ dt_w, const float* __restrict__ dt_b,
    const float* __restrict__ Ae, const float* __restrict__ Dp, int layer)
{
  // LDS regions (overlaid):
  //  R1: xr fp32 [35][132] -> xs in place (rows 0..31)                 18480B
  //  R2: XSh (xs hi bf16, [32][128] swizzled)                           8192B
  //  R3: {P1h,P1l} ([48][64] bf16 swizzled, 6144B each) -> {XSl 8192B, Dm 5632B}
  __shared__ __align__(16) char smem[18480 + 8192 + 13824];
  float* R1 = (float*)smem;
  short* XSh = (short*)(smem + 18480);
  short* P1h = (short*)(smem + 18480 + 8192);
  short* P1l = (short*)(smem + 18480 + 8192 + 6144);
  short* XSl = (short*)(smem + 18480 + 8192);
  float* Dm  = (float*)(smem + 18480 + 8192 + 8192);

  int tid = threadIdx.x;
  int tok0 = blockIdx.x * CH;
  int t0 = tok0 & (T-1);
  int dir = tok0 >> 14;
  int pb = dir*4 + layer;
  int wid = tid >> 6, lane = tid & 63;

  // ---- P0: residual + LN -> bf16 hi/lo direct to P1h/P1l (swizzled granules) ----
  {
    int wb = pb*64;
    float nwv = nw[wb+lane], nbv = nb[wb+lane];
    for (int r = wid; r < RP; r += 4) {
      float v = 0.f;
      if (r < ROWS && (r >= 3 || t0 != 0)) {
        int tok = tok0 - 3 + r;
        float hv = h[tok*64 + lane];
        float rr = (layer == 0) ? hv : hv + res_in[tok*64 + lane];
        if (r >= 3) res_out[tok*64 + lane] = rr;
        float sum = rr;
        #pragma unroll
        for (int o = 32; o > 0; o >>= 1) sum += __shfl_xor(sum, o);
        float mean = sum * (1.f/64.f);
        float df = rr - mean;
        float dv = df*df;
        #pragma unroll
        for (int o = 32; o > 0; o >>= 1) dv += __shfl_xor(dv, o);
        float inv = rsqrtf(dv*(1.f/64.f) + 1e-5f);
        v = df*inv*nwv + nbv;
      }
      unsigned short hb = bf16_rne(v);
      unsigned short lb = bf16_rne(v - bf16_to_f(hb));
      int g = lane >> 3, e = lane & 7;
      int off = r*64 + ((g ^ (r & 7)) << 3) + e;
      P1h[off] = (short)hb;
      P1l[off] = (short)lb;
    }
  }
  __syncthreads();
  // ---- P1: in-proj via MFMA bf16x3. A = tokens (LDS), B = weight rows (global). ----
  // wave w owns output rows [w*64, w*64+64). Rows 0..127 -> x (LDS R1); 128..255 -> z (global).
  {
    int mrow = lane & 15, kg = lane >> 4;
    for (int mt = 0; mt < 3; ++mt) {
      int trow = mt*16 + mrow;
      short8v ah[2], al[2];
      #pragma unroll
      for (int kt = 0; kt < 2; ++kt) {
        int g = kt*4 + kg;
        int offB = trow*128 + ((g ^ (trow & 7)) << 4);
        ah[kt] = *(const short8v*)((const char*)P1h + offB);
        al[kt] = *(const short8v*)((const char*)P1l + offB);
      }
      #pragma unroll
      for (int ntl = 0; ntl < 4; ++ntl) {
        int orow = wid*64 + ntl*16 + (lane & 15);
        f32x4 acc = {0.f, 0.f, 0.f, 0.f};
        #pragma unroll
        for (int kt = 0; kt < 2; ++kt) {
          size_t wo = (size_t)(pb*256 + orow)*64 + kt*32 + kg*8;
          short8v bh = *(const short8v*)(iwh + wo);
          short8v bl = *(const short8v*)(iwl + wo);
          acc = __builtin_amdgcn_mfma_f32_16x16x32_bf16(al[kt], bh, acc, 0, 0, 0);
          acc = __builtin_amdgcn_mfma_f32_16x16x32_bf16(ah[kt], bl, acc, 0, 0, 0);
          acc = __builtin_amdgcn_mfma_f32_16x16x32_bf16(ah[kt], bh, acc, 0, 0, 0);
        }
        int tokr = mt*16 + kg*4;
        if (wid < 2) {
          #pragma unroll
          for (int reg = 0; reg < 4; ++reg) {
            int trw = tokr + reg;
            if (trw < ROWS) R1[trw*XRS + orow] = acc[reg];
          }
        } else {
          int zc = orow - 128;
          #pragma unroll
          for (int reg = 0; reg < 4; ++reg) {
            int trw = tokr + reg;
            if (trw >= 3 && trw < ROWS) zb[(size_t)(tok0 + trw - 3)*128 + zc] = acc[reg];
          }
        }
      }
    }
  }
  __syncthreads();
  // ---- P2: causal conv + silu, in place over R1 (register-staged) ----
  {
    int d = tid & 127, tq = tid >> 7;
    int r0 = tq*16;
    float stage[19];
    #pragma unroll
    for (int i = 0; i < 19; ++i) stage[i] = R1[(r0+i)*XRS + d];
    float4 cwv = ((const float4*)(conv_w + (pb*128 + d)*4))[0];
    float cb = conv_b[pb*128 + d];
    __syncthreads();
    #pragma unroll
    for (int i = 0; i < 16; ++i) {
      float acc = cb + stage[i]*cwv.x + stage[i+1]*cwv.y + stage[i+2]*cwv.z + stage[i+3]*cwv.w;
      float xv = acc / (1.f + __expf(-acc));
      R1[(r0+i)*XRS + d] = xv;
    }
  }
  __syncthreads();
  // ---- P2b: xs -> bf16 hi/lo swizzled (XSh/XSl), 32 rows x 16 granules ----
  {
    for (int q = tid; q < 512; q += 256) {
      int row = q >> 4, g = q & 15;
      int sw = (g & 8) | ((g & 7) ^ (row & 7));
      const float* src = R1 + row*XRS + g*8;
      float4 f0 = ((const float4*)src)[0];
      float4 f1 = ((const float4*)src)[1];
      float fv[8] = {f0.x,f0.y,f0.z,f0.w,f1.x,f1.y,f1.z,f1.w};
      short8v vh, vl;
      #pragma unroll
      for (int e = 0; e < 8; ++e) {
        unsigned short hb = bf16_rne(fv[e]);
        vh[e] = (short)hb;
        vl[e] = (short)bf16_rne(fv[e] - bf16_to_f(hb));
      }
      *(short8v*)(XSh + row*128 + sw*8) = vh;
      *(short8v*)(XSl + row*128 + sw*8) = vl;
    }
  }
  __syncthreads();
  // ---- P3: x-proj via MFMA bf16x3 -> Dm[32][44]. waves 0,1 only (mt = wave). ----
  if (wid < 2) {
    int mrow = lane & 15, kg = lane >> 4;
    int trow = wid*16 + mrow;
    short8v ah[4], al[4];
    #pragma unroll
    for (int kt = 0; kt < 4; ++kt) {
      int g = kt*4 + kg;                 // 0..15
      int sw = (g & 8) | ((g & 7) ^ (trow & 7));
      ah[kt] = *(const short8v*)(XSh + trow*128 + sw*8);
      al[kt] = *(const short8v*)(XSl + trow*128 + sw*8);
    }
    #pragma unroll
    for (int ntl = 0; ntl < 3; ++ntl) {
      int n = ntl*16 + (lane & 15);
      f32x4 acc = {0.f, 0.f, 0.f, 0.f};
      #pragma unroll
      for (int kt = 0; kt < 4; ++kt) {
        size_t wo = (size_t)(pb*48 + n)*128 + kt*32 + kg*8;
        short8v bh = *(const short8v*)(xph + wo);
        short8v bl = *(const short8v*)(xpl + wo);
        acc = __builtin_amdgcn_mfma_f32_16x16x32_bf16(al[kt], bh, acc, 0, 0, 0);
        acc = __builtin_amdgcn_mfma_f32_16x16x32_bf16(ah[kt], bl, acc, 0, 0, 0);
        acc = __builtin_amdgcn_mfma_f32_16x16x32_bf16(ah[kt], bh, acc, 0, 0, 0);
      }
      if (n < 36) {
        int tokr = wid*16 + kg*4;
        #pragma unroll
        for (int reg = 0; reg < 4; ++reg) Dm[(tokr+reg)*DBLS + n] = acc[reg];
      }
    }
  }
  __syncthreads();
  // ---- Cg copy-out (C columns 20..35) ----
  for (int i = tid; i < 512; i += 256) {
    int tl = i >> 4, s = i & 15;
    Cg[(tok0 + tl)*16 + s] = Dm[tl*DBLS + 20 + s];
  }
  // ---- P5: local scan with fused dt (softplus) ----
  {
    int sd = tid >> 1, p = tid & 1, s0 = p*8;
    float ae[8];
    {
      const float4* A4 = (const float4*)(Ae + pb*2048 + sd*16 + s0);
      float4 a0 = A4[0], a1 = A4[1];
      ae[0]=a0.x; ae[1]=a0.y; ae[2]=a0.z; ae[3]=a0.w;
      ae[4]=a1.x; ae[5]=a1.y; ae[6]=a1.z; ae[7]=a1.w;
    }
    float Dv = Dp[pb*128 + sd];
    float4 dwv = ((const float4*)(dt_w + (pb*128 + sd)*4))[0];
    float dtbv = dt_b[pb*128 + sd];
    float hs[8] = {0,0,0,0,0,0,0,0};
    float cum = 0.f;
    for (int t = 0; t < CH; ++t) {
      float4 dr = *(const float4*)(Dm + t*DBLS);
      float dpre = dtbv + dr.x*dwv.x + dr.y*dwv.y + dr.z*dwv.z + dr.w*dwv.w;
      float dtv = fmaxf(dpre, 0.f) + __logf(1.f + __expf(-fabsf(dpre)));
      float xv = R1[t*XRS + sd];
      cum += dtv;
      float dtx = dtv*xv;
      const float4* B4 = (const float4*)(Dm + t*DBLS + 4 + s0);
      const float4* C4 = (const float4*)(Dm + t*DBLS + 20 + s0);
      float4 b0 = B4[0], b1 = B4[1];
      float4 c0 = C4[0], c1 = C4[1];
      float bv[8] = {b0.x,b0.y,b0.z,b0.w,b1.x,b1.y,b1.z,b1.w};
      float cv[8] = {c0.x,c0.y,c0.z,c0.w,c1.x,c1.y,c1.z,c1.w};
      float acc = 0.f;
      #pragma unroll
      for (int s = 0; s < 8; ++s) {
        float dA = exp2f(dtv*ae[s]);
        hs[s] = dA*hs[s] + dtx*bv[s];
        acc += hs[s]*cv[s];
      }
      acc += __shfl_xor(acc, 1);
      if (p == 0) {
        int tok = tok0 + t;
        ylocal[tok*128 + sd] = acc + xv*Dv;
        cumdt[tok*128 + sd] = cum;
      }
    }
    int base = blockIdx.x*2048 + sd*16 + s0;
    #pragma unroll
    for (int s = 0; s < 8; ++s) { hend[base+s] = hs[s]; Pst[base+s] = exp2f(ae[s]*cum); }
  }
}

// ---------------- kC: prefix across 64 chunks (Sinit in place over Pst) ----------------
__global__ __launch_bounds__(256) void kC(const float* __restrict__ hend, float* __restrict__ Pst) {
  int db = blockIdx.x >> 3;       // 128 blocks: db*8 + slice
  int e  = (blockIdx.x & 7)*256 + threadIdx.x;
  float init = 0.f;
  #pragma unroll 4
  for (int c = 0; c < NCH; ++c) {
    int base = (db*NCH + c)*2048 + e;
    float pz = Pst[base];
    float he = hend[base];
    Pst[base] = init;
    init = pz*init + he;
  }
}

// ============ kD: correction + gate -> LDS, then out-proj (R=2 tiled); 32 tokens/block ============
__global__ __launch_bounds__(256) void kD(
    const float* __restrict__ ylocal, const float* __restrict__ cumdt,
    const float* __restrict__ zb, const float* __restrict__ Cg,
    const float* __restrict__ Sinit, const float* __restrict__ Ae,
    const float* __restrict__ out_w, float* __restrict__ hout, int layer)
{
  __shared__ __align__(16) float ys[32*148];   // swizzled: col = (d>>5)*36 + (d&31)
  int tid = threadIdx.x;
  int tok0 = blockIdx.x * CH;
  int dir = tok0 >> 14;
  int pb = dir*4 + layer;
  // ---- phase 1: y = (ylocal + sum_s exp2(ae*cum)*Si*C) * silu(z) ----
  {
    int d = tid & 127, tg = tid >> 7;
    float ae[16], Si[16];
    {
      const float4* A4 = (const float4*)(Ae + pb*2048 + d*16);
      const float4* S4 = (const float4*)(Sinit + blockIdx.x*2048 + d*16);
      #pragma unroll
      for (int q = 0; q < 4; ++q) {
        float4 a = A4[q], s = S4[q];
        ae[q*4+0]=a.x; ae[q*4+1]=a.y; ae[q*4+2]=a.z; ae[q*4+3]=a.w;
        Si[q*4+0]=s.x; Si[q*4+1]=s.y; Si[q*4+2]=s.z; Si[q*4+3]=s.w;
      }
    }
    int col = (d >> 5)*36 + (d & 31);
    for (int i = 0; i < 16; ++i) {
      int tl = i*2 + tg;
      int tok = tok0 + tl;
      float cum = cumdt[tok*128 + d];
      const float4* C4 = (const float4*)(Cg + tok*16);
      float corr = 0.f;
      #pragma unroll
      for (int q = 0; q < 4; ++q) {
        float4 cc = C4[q];
        corr += exp2f(ae[q*4+0]*cum)*Si[q*4+0]*cc.x;
        corr += exp2f(ae[q*4+1]*cum)*Si[q*4+1]*cc.y;
        corr += exp2f(ae[q*4+2]*cum)*Si[q*4+2]*cc.z;
        corr += exp2f(ae[q*4+3]*cum)*Si[q*4+3]*cc.w;
      }
      float yl = ylocal[tok*128 + d];
      float zv = zb[tok*128 + d];
      ys[tl*148 + col] = (yl + corr) * (zv / (1.f + __expf(-zv)));
    }
  }
  __syncthreads();
  // ---- phase 2: out-proj; lane = (q, jj); wave = (row-half, token-half); 2 rows/lane ----
  {
    int lane = tid & 63, wid = tid >> 6;
    int q = lane >> 4, jj = lane & 15;
    int rh = wid >> 1, th = wid & 1;
    int j0 = rh*32 + jj;                 // rows j0 and j0+16
    const float4* W4a = (const float4*)(out_w + pb*8192 + j0*128 + q*32);
    const float4* W4b = (const float4*)(out_w + pb*8192 + (j0+16)*128 + q*32);
    float4 wa[8], wb8[8];
    #pragma unroll
    for (int i = 0; i < 8; ++i) wa[i] = W4a[i];
    #pragma unroll
    for (int i = 0; i < 8; ++i) wb8[i] = W4b[i];
    for (int t = th*16; t < th*16 + 16; ++t) {
      const float4* yv = (const float4*)(ys + t*148 + q*36);
      float a0 = 0.f, a1 = 0.f;
      #pragma unroll
      for (int i = 0; i < 8; ++i) {
        float4 vv = yv[i];
        a0 += vv.x*wa[i].x + vv.y*wa[i].y + vv.z*wa[i].z + vv.w*wa[i].w;
        a1 += vv.x*wb8[i].x + vv.y*wb8[i].y + vv.z*wb8[i].z + vv.w*wb8[i].w;
      }
      a0 += __shfl_xor(a0, 16); a0 += __shfl_xor(a0, 32);
      a1 += __shfl_xor(a1, 16); a1 += __shfl_xor(a1, 32);
      if (q == 0) {
        hout[(tok0 + t)*64 + j0]      = a0;
        hout[(tok0 + t)*64 + j0 + 16] = a1;
      }
    }
  }
}

// ---------------- k5: final residual add + LN + pool logits ----------------
__global__ void k5(const float* __restrict__ h, const float* __restrict__ res,
                   float* __restrict__ hfin, float* __restrict__ logits,
                   const float* __restrict__ nfw, const float* __restrict__ nfb,
                   const float* __restrict__ fpw, const float* __restrict__ fpb,
                   const float* __restrict__ bpw, const float* __restrict__ bpb) {
  int wid = threadIdx.x >> 6, lane = threadIdx.x & 63;
  int tok = blockIdx.x*4 + wid;
  int dir = tok >> 14;
  float r = h[tok*64 + lane] + res[tok*64 + lane];
  float sum = r;
  #pragma unroll
  for (int o = 32; o > 0; o >>= 1) sum += __shfl_xor(sum, o);
  float mean = sum * (1.f/64.f);
  float df = r - mean;
  float dv = df*df;
  #pragma unroll
  for (int o = 32; o > 0; o >>= 1) dv += __shfl_xor(dv, o);
  float inv = rsqrtf(dv*(1.f/64.f) + 1e-5f);
  float v = df*inv*nfw[lane] + nfb[lane];
  hfin[tok*64 + lane] = v;
  float lg = v * (dir ? bpw[lane] : fpw[lane]);
  #pragma unroll
  for (int o = 32; o > 0; o >>= 1) lg += __shfl_xor(lg, o);
  if (lane == 0) logits[tok] = lg + (dir ? bpb[0] : fpb[0]);
}

// ---------------- k6a: softmax stats per sequence ----------------
__global__ void k6a(const float* __restrict__ logits, float* __restrict__ stats) {
  int blk = blockIdx.x;           // 16
  int tid = threadIdx.x;          // 256
  int tok0 = blk*T;
  __shared__ float red[256];
  float mx = -1e30f;
  for (int t = tid; t < T; t += 256) mx = fmaxf(mx, logits[tok0 + t]);
  red[tid] = mx; __syncthreads();
  for (int o = 128; o > 0; o >>= 1) { if (tid < o) red[tid] = fmaxf(red[tid], red[tid+o]); __syncthreads(); }
  mx = red[0]; __syncthreads();
  float sm = 0.f;
  for (int t = tid; t < T; t += 256) sm += __expf(logits[tok0 + t] - mx);
  red[tid] = sm; __syncthreads();
  for (int o = 128; o > 0; o >>= 1) { if (tid < o) red[tid] += red[tid+o]; __syncthreads(); }
  if (tid == 0) { stats[blk] = mx; stats[16+blk] = 1.f/red[0]; }
}

// ---------------- k6b: sliced weighted pool ----------------
__global__ void k6b(const float* __restrict__ hfin, const float* __restrict__ logits,
                    const float* __restrict__ stats, float* __restrict__ pf) {
  int blk = blockIdx.x;            // 128 = seq*8 + slice
  int seq = blk >> 3, slice = blk & 7;
  int tid = threadIdx.x;
  int w = tid >> 6, m = tid & 63;
  float mx = stats[seq], inv = stats[16+seq];
  int tok0 = seq*T + slice*256;
  float pacc = 0.f;
  for (int t = w; t < 256; t += 4) {
    float a = __expf(logits[tok0 + t] - mx)*inv;
    pacc += a * hfin[(tok0 + t)*64 + m];
  }
  __shared__ float red[256];
  red[tid] = pacc; __syncthreads();
  if (w == 0) pf[(seq*64 + m)*8 + slice] = red[m] + red[64+m] + red[128+m] + red[192+m];
}

// ---------------- k6c: reduce slices ----------------
__global__ void k6c(const float* __restrict__ pf, float* __restrict__ pooled) {
  int i = blockIdx.x*256 + threadIdx.x;   // 1024
  if (i >= 1024) return;
  const float4* p4 = (const float4*)(pf + i*8);
  float4 a = p4[0], b = p4[1];
  pooled[i] = a.x+a.y+a.z+a.w+b.x+b.y+b.z+b.w;
}

// ---------------- k7: head ----------------
__global__ void k7(const float* __restrict__ pooled, float* __restrict__ out,
                   const float* __restrict__ llw, const float* __restrict__ llb) {
  int idx = blockIdx.x*256 + threadIdx.x;
  if (idx >= 512) return;
  int b = idx >> 6, j = idx & 63;
  float a = llb[j];
  for (int d = 0; d < 64; ++d) {
    a += pooled[b*64 + d]       * llw[j*128 + d];
    a += pooled[(8+b)*64 + d]   * llw[j*128 + 64 + d];
  }
  out[idx] = a;
}

extern "C" void kernel_launch(void* const* d_in, const int* in_sizes, int n_in,
                              void* d_out, int out_size, void* d_ws, size_t ws_size,
                              hipStream_t stream) {
  const float* x      = (const float*)d_in[0];
  const float* in_w   = (const float*)d_in[1];
  const float* conv_w = (const float*)d_in[2];
  const float* conv_b = (const float*)d_in[3];
  const float* xproj_w= (const float*)d_in[4];
  const float* dt_w   = (const float*)d_in[5];
  const float* dt_b   = (const float*)d_in[6];
  const float* A_log  = (const float*)d_in[7];
  const float* Dp     = (const float*)d_in[8];
  const float* out_w  = (const float*)d_in[9];
  const float* nw     = (const float*)d_in[10];
  const float* nb     = (const float*)d_in[11];
  const float* nfw    = (const float*)d_in[12];
  const float* nfb    = (const float*)d_in[13];
  const float* fpw    = (const float*)d_in[14];
  const float* fpb    = (const float*)d_in[15];
  const float* bpw    = (const float*)d_in[16];
  const float* bpb    = (const float*)d_in[17];
  const float* llw    = (const float*)d_in[18];
  const float* llb    = (const float*)d_in[19];
  float* ws  = (float*)d_ws;
  float* h      = ws;                    // 2M
  float* resA   = ws + 2097152;          // 2M
  float* resB   = ws + 4194304;          // 2M
  float* zb     = ws + 6291456;          // 4M
  float* ylocal = ws + 10485760;         // 4M
  float* cumdt  = ws + 14680064;         // 4M (hfin in tail)
  float* Cg     = ws + 18874368;         // 512K
  float* hend   = ws + 19398656;         // 2M
  float* Pst    = ws + 21495808;         // 2M (Sinit in place)
  float* logits = ws + 23592960;         // 32K
  float* pf     = ws + 23625728;         // 8K
  float* pooled = ws + 23633920;         // 1K
  float* stats  = ws + 23634944;         // 32
  float* AeBuf  = ws + 23634976;         // 16K
  unsigned short* iwh = (unsigned short*)(ws + 23651360);   // 131072 shorts
  unsigned short* iwl = (unsigned short*)(ws + 23716896);
  unsigned short* xph = (unsigned short*)(ws + 23782432);   // 49152 shorts
  unsigned short* xpl = (unsigned short*)(ws + 23807008);
  float* out    = (float*)d_out;

  k_prep<<<dim3(8192), dim3(256), 0, stream>>>(x, h);
  kAe   <<<dim3(64),   dim3(256), 0, stream>>>(A_log, AeBuf);
  kSplit<<<dim3(512),  dim3(256), 0, stream>>>(in_w, xproj_w, iwh, iwl, xph, xpl);
  for (int layer = 0; layer < 4; ++layer) {
    float* rin, *rout;
    if (layer == 0) { rin = resA; rout = resA; }
    else if (layer == 1) { rin = resA; rout = resB; }
    else if (layer == 2) { rin = resB; rout = resA; }
    else { rin = resA; rout = resB; }
    kA<<<dim3(1024), dim3(256), 0, stream>>>(h, rin, rout, zb, ylocal, cumdt, Cg, hend, Pst,
                                             iwh, iwl, xph, xpl, nw, nb, conv_w, conv_b,
                                             dt_w, dt_b, AeBuf, Dp, layer);
    kC<<<dim3(128), dim3(256), 0, stream>>>(hend, Pst);
    kD<<<dim3(1024), dim3(256), 0, stream>>>(ylocal, cumdt, zb, Cg, Pst, AeBuf, out_w, h, layer);
  }
  k5 <<<dim3(8192), dim3(256), 0, stream>>>(h, resB, cumdt, logits, nfw, nfb, fpw, fpb, bpw, bpb);
  k6a<<<dim3(16),   dim3(256), 0, stream>>>(logits, stats);
  k6b<<<dim3(128),  dim3(256), 0, stream>>>(cumdt, logits, stats, pf);
  k6c<<<dim3(4),    dim3(256), 0, stream>>>(pf, pooled);
  k7 <<<dim3(2),    dim3(256), 0, stream>>>(pooled, out, llw, llb);
}